// Round 1
// baseline (2643.022 us; speedup 1.0000x reference)
//
#include <hip/hip_runtime.h>

typedef unsigned short u16;
typedef unsigned int u32;
typedef __attribute__((ext_vector_type(8))) short short8;
typedef __attribute__((ext_vector_type(4))) float f32x4;

#define NB 2048
#define NTOK 49
#define CH 384
#define NH 12
#define HD 32
#define SCALE_Q 0.17677669529663687f

__device__ __forceinline__ u16 f2bf(float f) {
  u32 u = __float_as_uint(f);
  u += 0x7fffu + ((u >> 16) & 1u);
  return (u16)(u >> 16);
}
__device__ __forceinline__ float bf2f(u16 h) { return __uint_as_float(((u32)h) << 16); }
__device__ __forceinline__ u32 pk2(float a, float b) { return (u32)f2bf(a) | ((u32)f2bf(b) << 16); }

// ---------- prep: transpose projection weights to bf16, gather rpb ----------
__global__ void prep_kernel(const float* __restrict__ w_qkv, const float* __restrict__ w_proj,
                            const float* __restrict__ rpb_table, const int* __restrict__ rel_index,
                            u16* __restrict__ wqkvT, u16* __restrict__ wprojT, float* __restrict__ rpb)
{
  int idx = blockIdx.x * 256 + threadIdx.x;
  if (idx < 1152 * 384) {
    int n = idx / 384, k = idx - n * 384;
    wqkvT[idx] = f2bf(w_qkv[(size_t)k * 1152 + n]);
  } else if (idx < 1152 * 384 + 384 * 384) {
    int i2 = idx - 1152 * 384;
    int n = i2 / 384, k = i2 - n * 384;
    wprojT[i2] = f2bf(w_proj[(size_t)k * 384 + n]);
  } else if (idx < 1152 * 384 + 384 * 384 + 12 * 2401) {
    int i3 = idx - (1152 * 384 + 384 * 384);
    int hh = i3 / 2401, r = i3 - hh * 2401;
    rpb[i3] = rpb_table[(size_t)rel_index[r] * 12 + hh];
  }
}

// ---------- QKV GEMM: [100352,384] @ [384,1152(+768)] bf16 MFMA ----------
// grid (15, 784): nt 0..8 -> x1 cols 0..1151 ; nt 9..14 -> x2 cols 384..1151
__global__ __launch_bounds__(256) void gemm_qkv(
    const float* __restrict__ x1, const float* __restrict__ x2,
    const u16* __restrict__ wT, const float* __restrict__ bias,
    u16* __restrict__ q1, u16* __restrict__ k1, u16* __restrict__ v1,
    u16* __restrict__ k2, u16* __restrict__ v2)
{
  __shared__ __align__(16) u16 As[128 * 72];
  __shared__ __align__(16) u16 Bs[128 * 72];
  const int nt = blockIdx.x;
  const int mt = blockIdx.y;
  const bool isx2 = nt >= 9;
  const float* __restrict__ X = isx2 ? x2 : x1;
  const int colbase = isx2 ? 384 + (nt - 9) * 128 : nt * 128;
  const int m0 = mt * 128;
  const int tid = threadIdx.x;
  const int lane = tid & 63, wv = tid >> 6;
  const int wr = wv >> 1, wc = wv & 1;
  const int l15 = lane & 15, l4 = lane >> 4;

  f32x4 acc[4][4] = {};

  const int ar = tid >> 1;
  const int ak = (tid & 1) * 32;
  const float* xg = X + (size_t)(m0 + ar) * CH + ak;
  const u16* bg = wT + (size_t)(colbase + ar) * CH + ak;
  u16* asw = &As[ar * 72 + ak];
  u16* bsw = &Bs[ar * 72 + ak];

  for (int kk = 0; kk < CH; kk += 64) {
    float4 av[8];
#pragma unroll
    for (int u = 0; u < 8; ++u)
      av[u] = *reinterpret_cast<const float4*>(xg + kk + u * 4);
    uint4 bv[4];
#pragma unroll
    for (int u = 0; u < 4; ++u)
      bv[u] = *reinterpret_cast<const uint4*>(bg + kk + u * 8);
    __syncthreads();
#pragma unroll
    for (int u = 0; u < 8; ++u) {
      uint2 p;
      p.x = pk2(av[u].x, av[u].y);
      p.y = pk2(av[u].z, av[u].w);
      *reinterpret_cast<uint2*>(asw + u * 4) = p;
    }
#pragma unroll
    for (int u = 0; u < 4; ++u)
      *reinterpret_cast<uint4*>(bsw + u * 8) = bv[u];
    __syncthreads();
#pragma unroll
    for (int ks = 0; ks < 2; ++ks) {
      short8 af[4], bfr[4];
#pragma unroll
      for (int i = 0; i < 4; ++i)
        af[i] = *reinterpret_cast<const short8*>(&As[(wr * 64 + i * 16 + l15) * 72 + ks * 32 + l4 * 8]);
#pragma unroll
      for (int j = 0; j < 4; ++j)
        bfr[j] = *reinterpret_cast<const short8*>(&Bs[(wc * 64 + j * 16 + l15) * 72 + ks * 32 + l4 * 8]);
#pragma unroll
      for (int i = 0; i < 4; ++i)
#pragma unroll
        for (int j = 0; j < 4; ++j)
          acc[i][j] = __builtin_amdgcn_mfma_f32_16x16x32_bf16(af[i], bfr[j], acc[i][j], 0, 0, 0);
    }
  }

#pragma unroll
  for (int j = 0; j < 4; ++j) {
    const int col = colbase + wc * 64 + j * 16 + l15;
    const float bb = bias[col];
    u16* dst;
    float scl = 1.0f;
    int cm;
    if (col < 384)      { dst = q1; scl = SCALE_Q; cm = col; }
    else if (col < 768) { dst = isx2 ? k2 : k1;    cm = col - 384; }
    else                { dst = isx2 ? v2 : v1;    cm = col - 768; }
    const int h = cm >> 5, d = cm & 31;
#pragma unroll
    for (int i = 0; i < 4; ++i) {
#pragma unroll
      for (int r = 0; r < 4; ++r) {
        const int gm = m0 + wr * 64 + i * 16 + l4 * 4 + r;
        const int b = gm / 49, tok = gm - b * 49;
        const float val = (acc[i][j][r] + bb) * scl;
        dst[(((size_t)b * NH + h) * NTOK + tok) * HD + d] = f2bf(val);
      }
    }
  }
}

// ---------- attention: one block per (b,h), f32 VALU ----------
__global__ __launch_bounds__(256) void attn_kernel(
    const u16* __restrict__ q1, const u16* __restrict__ k1, const u16* __restrict__ v1,
    const u16* __restrict__ k2, const u16* __restrict__ v2,
    const float* __restrict__ mask1, const float* __restrict__ mask2,
    const float* __restrict__ rpb, float* __restrict__ outw)
{
  __shared__ __align__(16) float qs[49 * 32];
  __shared__ __align__(16) float kT[32 * 104];   // [k][j], j 0..48 = k1, 49..97 = k2
  __shared__ __align__(16) float vs[98 * 32];    // rows 0..48 = v1, 49..97 = v2
  __shared__ __align__(16) float Es[49 * 100];   // logits -> exp
  __shared__ float sinv[98];

  const int h = blockIdx.x, b = blockIdx.y;
  const int tid = threadIdx.x;
  const size_t base = ((size_t)b * NH + h) * (NTOK * HD);

  for (int e = tid; e < 1568; e += 256) qs[e] = bf2f(q1[base + e]);
  for (int e = tid; e < 1568; e += 256) {
    int j = e >> 5, kkk = e & 31;
    kT[kkk * 104 + j]      = bf2f(k1[base + e]);
    kT[kkk * 104 + 49 + j] = bf2f(k2[base + e]);
  }
  for (int e = tid; e < 1568; e += 256) {
    vs[e]        = bf2f(v1[base + e]);
    vs[1568 + e] = bf2f(v2[base + e]);
  }
  __syncthreads();

  const int wb = b & 63;
  const float* rp = rpb + h * 2401;
  const float* m1 = mask1 + (size_t)wb * 2401;
  const float* m2 = mask2 + (size_t)wb * 2401;

  // logits: 49 rows x 25 j-blocks of 4
  for (int it = tid; it < 49 * 25; it += 256) {
    int i = it / 25, jb = (it - i * 25) * 4;
    float a0 = 0.f, a1 = 0.f, a2 = 0.f, a3 = 0.f;
#pragma unroll
    for (int kkk = 0; kkk < 32; ++kkk) {
      float qv = qs[i * 32 + kkk];
      float4 kv = *reinterpret_cast<const float4*>(&kT[kkk * 104 + jb]);
      a0 += qv * kv.x; a1 += qv * kv.y; a2 += qv * kv.z; a3 += qv * kv.w;
    }
    float av[4] = {a0, a1, a2, a3};
#pragma unroll
    for (int u = 0; u < 4; ++u) {
      int j = jb + u;
      if (j < 98) {
        int p = (j >= 49) ? 1 : 0, jh = j - p * 49;
        float bias = rp[i * 49 + jh] + (p ? m2[i * 49 + jh] : m1[i * 49 + jh]);
        Es[i * 100 + j] = av[u] + bias;
      }
    }
  }
  __syncthreads();

  // softmax over 49 keys for each of 98 (row, half) pairs; one wave per row
  const int wv = tid >> 6, lane = tid & 63;
  for (int t = wv; t < 98; t += 4) {
    int i = t >> 1, p = t & 1;
    float* row = &Es[i * 100 + p * 49];
    float x = (lane < 49) ? row[lane] : -1e30f;
#pragma unroll
    for (int off = 32; off; off >>= 1) x = fmaxf(x, __shfl_xor(x, off));
    float e = 0.f;
    if (lane < 49) { e = __expf(row[lane] - x); row[lane] = e; }
    float s = e;
#pragma unroll
    for (int off = 32; off; off >>= 1) s += __shfl_xor(s, off);
    if (lane == 0) sinv[i * 2 + p] = 1.f / s;
  }
  __syncthreads();

  // PV: 49 rows x 16 col-blocks of 4 (64 out cols = v1|v2)
  const size_t wbase = (size_t)b * NTOK * 768;
  for (int it = tid; it < 49 * 16; it += 256) {
    int i = it / 16, cb = (it - i * 16) * 4;
    int p = cb >> 5, dd = cb & 31;
    float o0 = 0.f, o1 = 0.f, o2 = 0.f, o3 = 0.f;
    const float* Ei = &Es[i * 100 + p * 49];
    const float* vp = &vs[p * 1568 + dd];
#pragma unroll
    for (int jj = 0; jj < 49; ++jj) {
      float e = Ei[jj];
      float4 vvv = *reinterpret_cast<const float4*>(vp + jj * 32);
      o0 += e * vvv.x; o1 += e * vvv.y; o2 += e * vvv.z; o3 += e * vvv.w;
    }
    float si = sinv[i * 2 + p];
    float4 o = {o0 * si, o1 * si, o2 * si, o3 * si};
    *reinterpret_cast<float4*>(&outw[wbase + (size_t)i * 768 + p * 384 + h * 32 + dd]) = o;
  }
}

// ---------- proj GEMM: weights[:, :384] @ w_proj + b_proj ----------
__global__ __launch_bounds__(256) void gemm_proj(
    const float* __restrict__ Wsrc, const u16* __restrict__ wT,
    const float* __restrict__ bias, float* __restrict__ outx)
{
  __shared__ __align__(16) u16 As[128 * 72];
  __shared__ __align__(16) u16 Bs[128 * 72];
  const int nt = blockIdx.x;
  const int mt = blockIdx.y;
  const int colbase = nt * 128;
  const int m0 = mt * 128;
  const int tid = threadIdx.x;
  const int lane = tid & 63, wv = tid >> 6;
  const int wr = wv >> 1, wc = wv & 1;
  const int l15 = lane & 15, l4 = lane >> 4;

  f32x4 acc[4][4] = {};

  const int ar = tid >> 1;
  const int ak = (tid & 1) * 32;
  const float* xg = Wsrc + (size_t)(m0 + ar) * 768 + ak;
  const u16* bg = wT + (size_t)(colbase + ar) * CH + ak;
  u16* asw = &As[ar * 72 + ak];
  u16* bsw = &Bs[ar * 72 + ak];

  for (int kk = 0; kk < CH; kk += 64) {
    float4 av[8];
#pragma unroll
    for (int u = 0; u < 8; ++u)
      av[u] = *reinterpret_cast<const float4*>(xg + kk + u * 4);
    uint4 bv[4];
#pragma unroll
    for (int u = 0; u < 4; ++u)
      bv[u] = *reinterpret_cast<const uint4*>(bg + kk + u * 8);
    __syncthreads();
#pragma unroll
    for (int u = 0; u < 8; ++u) {
      uint2 p;
      p.x = pk2(av[u].x, av[u].y);
      p.y = pk2(av[u].z, av[u].w);
      *reinterpret_cast<uint2*>(asw + u * 4) = p;
    }
#pragma unroll
    for (int u = 0; u < 4; ++u)
      *reinterpret_cast<uint4*>(bsw + u * 8) = bv[u];
    __syncthreads();
#pragma unroll
    for (int ks = 0; ks < 2; ++ks) {
      short8 af[4], bfr[4];
#pragma unroll
      for (int i = 0; i < 4; ++i)
        af[i] = *reinterpret_cast<const short8*>(&As[(wr * 64 + i * 16 + l15) * 72 + ks * 32 + l4 * 8]);
#pragma unroll
      for (int j = 0; j < 4; ++j)
        bfr[j] = *reinterpret_cast<const short8*>(&Bs[(wc * 64 + j * 16 + l15) * 72 + ks * 32 + l4 * 8]);
#pragma unroll
      for (int i = 0; i < 4; ++i)
#pragma unroll
        for (int j = 0; j < 4; ++j)
          acc[i][j] = __builtin_amdgcn_mfma_f32_16x16x32_bf16(af[i], bfr[j], acc[i][j], 0, 0, 0);
    }
  }

#pragma unroll
  for (int j = 0; j < 4; ++j) {
    const int col = colbase + wc * 64 + j * 16 + l15;
    const float bb = bias[col];
#pragma unroll
    for (int i = 0; i < 4; ++i) {
#pragma unroll
      for (int r = 0; r < 4; ++r) {
        const int gm = m0 + wr * 64 + i * 16 + l4 * 4 + r;
        outx[(size_t)gm * CH + col] = acc[i][j][r] + bb;
      }
    }
  }
}

extern "C" void kernel_launch(void* const* d_in, const int* in_sizes, int n_in,
                              void* d_out, int out_size, void* d_ws, size_t ws_size,
                              hipStream_t stream) {
  const float* x1        = (const float*)d_in[0];
  const float* x2        = (const float*)d_in[1];
  const float* mask1     = (const float*)d_in[2];
  const float* mask2     = (const float*)d_in[3];
  const float* w_qkv     = (const float*)d_in[4];
  const float* b_qkv     = (const float*)d_in[5];
  const float* w_proj    = (const float*)d_in[6];
  const float* b_proj    = (const float*)d_in[7];
  const float* rpb_table = (const float*)d_in[8];
  const int*   rel_index = (const int*)d_in[9];

  float* outx = (float*)d_out;                      // [2048,49,384] f32 = 154,140,672 B
  const size_t SZe = (size_t)NB * NH * NTOK * HD;   // 38,535,168 elements
  float* outw = outx + SZe;                         // [2048,49,768] f32

  // q1,k1 (bf16) live in the x-region of d_out (exactly 154,140,672 B); proj writes x last.
  u16* q1 = (u16*)d_out;
  u16* k1 = q1 + SZe;

  u16* v1 = (u16*)d_ws;
  u16* k2 = v1 + SZe;
  u16* v2 = k2 + SZe;
  u16* wqkvT  = v2 + SZe;              // [1152][384] bf16
  u16* wprojT = wqkvT + 1152 * 384;    // [384][384] bf16
  float* rpb  = (float*)(wprojT + 384 * 384);  // [12][49][49] f32

  {
    int total = 1152 * 384 + 384 * 384 + 12 * 2401;
    prep_kernel<<<(total + 255) / 256, 256, 0, stream>>>(w_qkv, w_proj, rpb_table, rel_index,
                                                         wqkvT, wprojT, rpb);
  }
  gemm_qkv<<<dim3(15, 784), 256, 0, stream>>>(x1, x2, wqkvT, b_qkv, q1, k1, v1, k2, v2);
  attn_kernel<<<dim3(12, 2048), 256, 0, stream>>>(q1, k1, v1, k2, v2, mask1, mask2, rpb, outw);
  gemm_proj<<<dim3(3, 784), 256, 0, stream>>>(outw, wprojT, b_proj, outx);
}

// Round 2
// 1338.909 us; speedup vs baseline: 1.9740x; 1.9740x over previous
//
#include <hip/hip_runtime.h>

typedef unsigned short u16;
typedef unsigned int u32;
typedef __attribute__((ext_vector_type(8))) short short8;
typedef __attribute__((ext_vector_type(4))) float f32x4;

#define NB 2048
#define NTOK 49
#define CH 384
#define NH 12
#define HD 32
#define SCALE_Q 0.17677669529663687f

__device__ __forceinline__ u16 f2bf(float f) {
  u32 u = __float_as_uint(f);
  u += 0x7fffu + ((u >> 16) & 1u);
  return (u16)(u >> 16);
}
__device__ __forceinline__ float bf2f(u16 h) { return __uint_as_float(((u32)h) << 16); }
__device__ __forceinline__ u32 pk2(float a, float b) { return (u32)f2bf(a) | ((u32)f2bf(b) << 16); }

// ---------- prep: transpose projection weights to bf16, gather rpb ----------
__global__ void prep_kernel(const float* __restrict__ w_qkv, const float* __restrict__ w_proj,
                            const float* __restrict__ rpb_table, const int* __restrict__ rel_index,
                            u16* __restrict__ wqkvT, u16* __restrict__ wprojT, float* __restrict__ rpb)
{
  int idx = blockIdx.x * 256 + threadIdx.x;
  if (idx < 1152 * 384) {
    int n = idx / 384, k = idx - n * 384;
    wqkvT[idx] = f2bf(w_qkv[(size_t)k * 1152 + n]);
  } else if (idx < 1152 * 384 + 384 * 384) {
    int i2 = idx - 1152 * 384;
    int n = i2 / 384, k = i2 - n * 384;
    wprojT[i2] = f2bf(w_proj[(size_t)k * 384 + n]);
  } else if (idx < 1152 * 384 + 384 * 384 + 12 * 2401) {
    int i3 = idx - (1152 * 384 + 384 * 384);
    int hh = i3 / 2401, r = i3 - hh * 2401;
    rpb[i3] = rpb_table[(size_t)rel_index[r] * 12 + hh];
  }
}

// ---------- QKV GEMM: [100352,384] @ [384,1152(+768)] bf16 MFMA ----------
// q/k written [b,h,tok,d]; v written TRANSPOSED [b,h,d,tok] for attn's PV B-fragments.
__global__ __launch_bounds__(256) void gemm_qkv(
    const float* __restrict__ x1, const float* __restrict__ x2,
    const u16* __restrict__ wT, const float* __restrict__ bias,
    u16* __restrict__ q1, u16* __restrict__ k1, u16* __restrict__ vT1,
    u16* __restrict__ k2, u16* __restrict__ vT2)
{
  __shared__ __align__(16) u16 As[128 * 72];
  __shared__ __align__(16) u16 Bs[128 * 72];
  const int nt = blockIdx.x;
  const int mt = blockIdx.y;
  const bool isx2 = nt >= 9;
  const float* __restrict__ X = isx2 ? x2 : x1;
  const int colbase = isx2 ? 384 + (nt - 9) * 128 : nt * 128;
  const int m0 = mt * 128;
  const int tid = threadIdx.x;
  const int lane = tid & 63, wv = tid >> 6;
  const int wr = wv >> 1, wc = wv & 1;
  const int l15 = lane & 15, l4 = lane >> 4;

  f32x4 acc[4][4] = {};

  const int ar = tid >> 1;
  const int ak = (tid & 1) * 32;
  const float* xg = X + (size_t)(m0 + ar) * CH + ak;
  const u16* bg = wT + (size_t)(colbase + ar) * CH + ak;
  u16* asw = &As[ar * 72 + ak];
  u16* bsw = &Bs[ar * 72 + ak];

  for (int kk = 0; kk < CH; kk += 64) {
    float4 av[8];
#pragma unroll
    for (int u = 0; u < 8; ++u)
      av[u] = *reinterpret_cast<const float4*>(xg + kk + u * 4);
    uint4 bv[4];
#pragma unroll
    for (int u = 0; u < 4; ++u)
      bv[u] = *reinterpret_cast<const uint4*>(bg + kk + u * 8);
    __syncthreads();
#pragma unroll
    for (int u = 0; u < 8; ++u) {
      uint2 p;
      p.x = pk2(av[u].x, av[u].y);
      p.y = pk2(av[u].z, av[u].w);
      *reinterpret_cast<uint2*>(asw + u * 4) = p;
    }
#pragma unroll
    for (int u = 0; u < 4; ++u)
      *reinterpret_cast<uint4*>(bsw + u * 8) = bv[u];
    __syncthreads();
#pragma unroll
    for (int ks = 0; ks < 2; ++ks) {
      short8 af[4], bfr[4];
#pragma unroll
      for (int i = 0; i < 4; ++i)
        af[i] = *reinterpret_cast<const short8*>(&As[(wr * 64 + i * 16 + l15) * 72 + ks * 32 + l4 * 8]);
#pragma unroll
      for (int j = 0; j < 4; ++j)
        bfr[j] = *reinterpret_cast<const short8*>(&Bs[(wc * 64 + j * 16 + l15) * 72 + ks * 32 + l4 * 8]);
#pragma unroll
      for (int i = 0; i < 4; ++i)
#pragma unroll
        for (int j = 0; j < 4; ++j)
          acc[i][j] = __builtin_amdgcn_mfma_f32_16x16x32_bf16(af[i], bfr[j], acc[i][j], 0, 0, 0);
    }
  }

#pragma unroll
  for (int j = 0; j < 4; ++j) {
    const int col = colbase + wc * 64 + j * 16 + l15;
    const float bb = bias[col];
    u16* dst;
    float scl = 1.0f;
    bool isv = false;
    int cm;
    if (col < 384)      { dst = q1; scl = SCALE_Q; cm = col; }
    else if (col < 768) { dst = isx2 ? k2 : k1;    cm = col - 384; }
    else                { dst = isx2 ? vT2 : vT1;  cm = col - 768; isv = true; }
    const int h = cm >> 5, d = cm & 31;
#pragma unroll
    for (int i = 0; i < 4; ++i) {
#pragma unroll
      for (int r = 0; r < 4; ++r) {
        const int gm = m0 + wr * 64 + i * 16 + l4 * 4 + r;
        const int b = gm / 49, tok = gm - b * 49;
        const float val = (acc[i][j][r] + bb) * scl;
        const size_t addr = isv
            ? (((size_t)b * NH + h) * HD + d) * NTOK + tok
            : (((size_t)b * NH + h) * NTOK + tok) * HD + d;
        dst[addr] = f2bf(val);
      }
    }
  }
}

// ---------- attention: one block per (b,h), 4 waves, MFMA ----------
// Wave mt owns output rows mt*16..mt*16+15. S = Q@K^T via 16x16x32 (K=32 exact),
// softmax in-register (row spans the 16 lanes sharing l4), P->LDS bf16 (wave-private
// rows, no barrier needed), PV = P@V with V^T staged in LDS (stride-72 rows).
__global__ __launch_bounds__(256) void attn_kernel(
    const u16* __restrict__ q1, const u16* __restrict__ k1, const u16* __restrict__ vT1,
    const u16* __restrict__ k2, const u16* __restrict__ vT2,
    const float* __restrict__ mask1, const float* __restrict__ mask2,
    const float* __restrict__ rpb, float* __restrict__ outw)
{
  __shared__ __align__(16) u16 VT[2][32][72];  // [half][d][j], j padded to 64 (49.. zeroed)
  __shared__ __align__(16) u16 Pl[64][72];     // [i][j], wave-private row stripes

  const int h = blockIdx.x, b = blockIdx.y;
  const int tid = threadIdx.x;
  const int lane = tid & 63, mt = tid >> 6;
  const int l15 = lane & 15, l4 = lane >> 4;
  const size_t base = ((size_t)b * NH + h) * 1568;   // 1568 = 49*32 = 32*49

  // stage V^T (both halves): vT is [d][tok] contiguous per (b,h)
  for (int e = tid; e < 1568; e += 256) {
    int d = e / 49, j = e - d * 49;
    VT[0][d][j] = vT1[base + e];
    VT[1][d][j] = vT2[base + e];
  }
  // zero pad columns 49..63
  for (int e = tid; e < 2 * 32 * 15; e += 256) {
    int p = (e >= 480) ? 1 : 0;
    int e2 = e - p * 480;
    int d = e2 / 15, j = 49 + (e2 - d * 15);
    VT[p][d][j] = 0;
  }

  // Q A-fragment: rows mt*16+l15 (rows >=49 read garbage; discarded at output)
  const short8 aq = *reinterpret_cast<const short8*>(&q1[base + (mt * 16 + l15) * 32 + l4 * 8]);

  __syncthreads();

  const int wb = b & 63;
  const float* rp = rpb + h * 2401;
  const size_t obase = (size_t)b * (NTOK * 768) + (size_t)h * 32;

#pragma unroll
  for (int p = 0; p < 2; ++p) {
    const u16* __restrict__ kp = p ? k2 : k1;
    const float* __restrict__ msk = (p ? mask2 : mask1) + (size_t)wb * 2401;

    // S = Q @ K^T : 4 col-tiles, K=32 in one mfma each
    f32x4 s[4];
#pragma unroll
    for (int n = 0; n < 4; ++n) {
      short8 bk = *reinterpret_cast<const short8*>(&kp[base + (n * 16 + l15) * 32 + l4 * 8]);
      s[n] = __builtin_amdgcn_mfma_f32_16x16x32_bf16(aq, bk, (f32x4){0.f, 0.f, 0.f, 0.f}, 0, 0, 0);
    }

    // bias add + invalid-column kill (-1e30 -> exp()==0 zero-pads P)
#pragma unroll
    for (int r = 0; r < 4; ++r) {
      const int i = mt * 16 + l4 * 4 + r;
#pragma unroll
      for (int n = 0; n < 4; ++n) {
        const int j = n * 16 + l15;
        float v = s[n][r];
        if (j < 49) { if (i < 49) v += rp[i * 49 + j] + msk[i * 49 + j]; }
        else v = -1e30f;
        s[n][r] = v;
      }
    }

    // softmax per row r: reduce across the 16 lanes sharing l4 (xor 1,2,4,8)
#pragma unroll
    for (int r = 0; r < 4; ++r) {
      float mx = fmaxf(fmaxf(s[0][r], s[1][r]), fmaxf(s[2][r], s[3][r]));
      mx = fmaxf(mx, __shfl_xor(mx, 1));
      mx = fmaxf(mx, __shfl_xor(mx, 2));
      mx = fmaxf(mx, __shfl_xor(mx, 4));
      mx = fmaxf(mx, __shfl_xor(mx, 8));
      float e0 = __expf(s[0][r] - mx), e1 = __expf(s[1][r] - mx);
      float e2 = __expf(s[2][r] - mx), e3 = __expf(s[3][r] - mx);
      float sm = (e0 + e1) + (e2 + e3);
      sm += __shfl_xor(sm, 1);
      sm += __shfl_xor(sm, 2);
      sm += __shfl_xor(sm, 4);
      sm += __shfl_xor(sm, 8);
      const float si = 1.f / sm;
      s[0][r] = e0 * si; s[1][r] = e1 * si; s[2][r] = e2 * si; s[3][r] = e3 * si;
    }

    // P -> LDS (bf16), wave-private rows
#pragma unroll
    for (int n = 0; n < 4; ++n)
#pragma unroll
      for (int r = 0; r < 4; ++r)
        Pl[mt * 16 + l4 * 4 + r][n * 16 + l15] = f2bf(s[n][r]);

    // O = P @ V : K=64 (2 steps), N=32 (2 tiles)
    f32x4 o[2] = {};
#pragma unroll
    for (int kt = 0; kt < 2; ++kt) {
      short8 ap = *reinterpret_cast<const short8*>(&Pl[mt * 16 + l15][kt * 32 + l4 * 8]);
#pragma unroll
      for (int n2 = 0; n2 < 2; ++n2) {
        short8 bvf = *reinterpret_cast<const short8*>(&VT[p][n2 * 16 + l15][kt * 32 + l4 * 8]);
        o[n2] = __builtin_amdgcn_mfma_f32_16x16x32_bf16(ap, bvf, o[n2], 0, 0, 0);
      }
    }

    // out: weights[b, i, p*384 + h*32 + d]
#pragma unroll
    for (int n2 = 0; n2 < 2; ++n2)
#pragma unroll
      for (int r = 0; r < 4; ++r) {
        const int i = mt * 16 + l4 * 4 + r;
        if (i < 49)
          outw[obase + (size_t)i * 768 + p * 384 + n2 * 16 + l15] = o[n2][r];
      }
  }
}

// ---------- proj GEMM: weights[:, :384] @ w_proj + b_proj ----------
__global__ __launch_bounds__(256) void gemm_proj(
    const float* __restrict__ Wsrc, const u16* __restrict__ wT,
    const float* __restrict__ bias, float* __restrict__ outx)
{
  __shared__ __align__(16) u16 As[128 * 72];
  __shared__ __align__(16) u16 Bs[128 * 72];
  const int nt = blockIdx.x;
  const int mt = blockIdx.y;
  const int colbase = nt * 128;
  const int m0 = mt * 128;
  const int tid = threadIdx.x;
  const int lane = tid & 63, wv = tid >> 6;
  const int wr = wv >> 1, wc = wv & 1;
  const int l15 = lane & 15, l4 = lane >> 4;

  f32x4 acc[4][4] = {};

  const int ar = tid >> 1;
  const int ak = (tid & 1) * 32;
  const float* xg = Wsrc + (size_t)(m0 + ar) * 768 + ak;
  const u16* bg = wT + (size_t)(colbase + ar) * CH + ak;
  u16* asw = &As[ar * 72 + ak];
  u16* bsw = &Bs[ar * 72 + ak];

  for (int kk = 0; kk < CH; kk += 64) {
    float4 av[8];
#pragma unroll
    for (int u = 0; u < 8; ++u)
      av[u] = *reinterpret_cast<const float4*>(xg + kk + u * 4);
    uint4 bv[4];
#pragma unroll
    for (int u = 0; u < 4; ++u)
      bv[u] = *reinterpret_cast<const uint4*>(bg + kk + u * 8);
    __syncthreads();
#pragma unroll
    for (int u = 0; u < 8; ++u) {
      uint2 p;
      p.x = pk2(av[u].x, av[u].y);
      p.y = pk2(av[u].z, av[u].w);
      *reinterpret_cast<uint2*>(asw + u * 4) = p;
    }
#pragma unroll
    for (int u = 0; u < 4; ++u)
      *reinterpret_cast<uint4*>(bsw + u * 8) = bv[u];
    __syncthreads();
#pragma unroll
    for (int ks = 0; ks < 2; ++ks) {
      short8 af[4], bfr[4];
#pragma unroll
      for (int i = 0; i < 4; ++i)
        af[i] = *reinterpret_cast<const short8*>(&As[(wr * 64 + i * 16 + l15) * 72 + ks * 32 + l4 * 8]);
#pragma unroll
      for (int j = 0; j < 4; ++j)
        bfr[j] = *reinterpret_cast<const short8*>(&Bs[(wc * 64 + j * 16 + l15) * 72 + ks * 32 + l4 * 8]);
#pragma unroll
      for (int i = 0; i < 4; ++i)
#pragma unroll
        for (int j = 0; j < 4; ++j)
          acc[i][j] = __builtin_amdgcn_mfma_f32_16x16x32_bf16(af[i], bfr[j], acc[i][j], 0, 0, 0);
    }
  }

#pragma unroll
  for (int j = 0; j < 4; ++j) {
    const int col = colbase + wc * 64 + j * 16 + l15;
    const float bb = bias[col];
#pragma unroll
    for (int i = 0; i < 4; ++i) {
#pragma unroll
      for (int r = 0; r < 4; ++r) {
        const int gm = m0 + wr * 64 + i * 16 + l4 * 4 + r;
        outx[(size_t)gm * CH + col] = acc[i][j][r] + bb;
      }
    }
  }
}

extern "C" void kernel_launch(void* const* d_in, const int* in_sizes, int n_in,
                              void* d_out, int out_size, void* d_ws, size_t ws_size,
                              hipStream_t stream) {
  const float* x1        = (const float*)d_in[0];
  const float* x2        = (const float*)d_in[1];
  const float* mask1     = (const float*)d_in[2];
  const float* mask2     = (const float*)d_in[3];
  const float* w_qkv     = (const float*)d_in[4];
  const float* b_qkv     = (const float*)d_in[5];
  const float* w_proj    = (const float*)d_in[6];
  const float* b_proj    = (const float*)d_in[7];
  const float* rpb_table = (const float*)d_in[8];
  const int*   rel_index = (const int*)d_in[9];

  float* outx = (float*)d_out;                      // [2048,49,384] f32
  const size_t SZe = (size_t)NB * NH * NTOK * HD;   // 38,535,168 elements
  float* outw = outx + SZe;                         // [2048,49,768] f32

  // q1,k1 (bf16) live in the x-region of d_out; proj writes x last.
  u16* q1 = (u16*)d_out;
  u16* k1 = q1 + SZe;

  u16* vT1 = (u16*)d_ws;
  u16* k2  = vT1 + SZe;
  u16* vT2 = k2 + SZe;
  u16* wqkvT  = vT2 + SZe;             // [1152][384] bf16
  u16* wprojT = wqkvT + 1152 * 384;    // [384][384] bf16
  float* rpb  = (float*)(wprojT + 384 * 384);  // [12][49][49] f32

  {
    int total = 1152 * 384 + 384 * 384 + 12 * 2401;
    prep_kernel<<<(total + 255) / 256, 256, 0, stream>>>(w_qkv, w_proj, rpb_table, rel_index,
                                                         wqkvT, wprojT, rpb);
  }
  gemm_qkv<<<dim3(15, 784), 256, 0, stream>>>(x1, x2, wqkvT, b_qkv, q1, k1, vT1, k2, vT2);
  attn_kernel<<<dim3(12, 2048), 256, 0, stream>>>(q1, k1, vT1, k2, vT2, mask1, mask2, rpb, outw);
  gemm_proj<<<dim3(3, 784), 256, 0, stream>>>(outw, wprojT, b_proj, outx);
}

// Round 3
// 1163.073 us; speedup vs baseline: 2.2724x; 1.1512x over previous
//
#include <hip/hip_runtime.h>

typedef unsigned short u16;
typedef unsigned int u32;
typedef __attribute__((ext_vector_type(8))) short short8;
typedef __attribute__((ext_vector_type(4))) float f32x4;

#define NB 2048
#define NTOK 49
#define CH 384
#define NH 12
#define HD 32
#define SCALE_Q 0.17677669529663687f

__device__ __forceinline__ u16 f2bf(float f) {
  u32 u = __float_as_uint(f);
  u += 0x7fffu + ((u >> 16) & 1u);
  return (u16)(u >> 16);
}
__device__ __forceinline__ float bf2f(u16 h) { return __uint_as_float(((u32)h) << 16); }
__device__ __forceinline__ u32 pk2(float a, float b) { return (u32)f2bf(a) | ((u32)f2bf(b) << 16); }

// ---------- prep: transpose projection weights to bf16, gather rpb ----------
__global__ void prep_kernel(const float* __restrict__ w_qkv, const float* __restrict__ w_proj,
                            const float* __restrict__ rpb_table, const int* __restrict__ rel_index,
                            u16* __restrict__ wqkvT, u16* __restrict__ wprojT, float* __restrict__ rpb)
{
  int idx = blockIdx.x * 256 + threadIdx.x;
  if (idx < 1152 * 384) {
    int n = idx / 384, k = idx - n * 384;
    wqkvT[idx] = f2bf(w_qkv[(size_t)k * 1152 + n]);
  } else if (idx < 1152 * 384 + 384 * 384) {
    int i2 = idx - 1152 * 384;
    int n = i2 / 384, k = i2 - n * 384;
    wprojT[i2] = f2bf(w_proj[(size_t)k * 384 + n]);
  } else if (idx < 1152 * 384 + 384 * 384 + 12 * 2401) {
    int i3 = idx - (1152 * 384 + 384 * 384);
    int hh = i3 / 2401, r = i3 - hh * 2401;
    rpb[i3] = rpb_table[(size_t)rel_index[r] * 12 + hh];
  }
}

// ---------- QKV GEMM: [100352,384] @ [384,1152(+768)] bf16 MFMA ----------
// All of q/k/v written [b,h,tok,d]. Epilogue re-layouts through LDS for fully
// coalesced 64B-line writes. XCD-chunked block swizzle for A-tile L2 reuse.
__global__ __launch_bounds__(256) void gemm_qkv(
    const float* __restrict__ x1, const float* __restrict__ x2,
    const u16* __restrict__ wT, const float* __restrict__ bias,
    u16* __restrict__ q1, u16* __restrict__ k1, u16* __restrict__ v1,
    u16* __restrict__ k2, u16* __restrict__ v2)
{
  __shared__ __align__(16) u16 smem[128 * 152];  // 38912 B
  u16* As = smem;               // [128][72] during K-loop
  u16* Bs = smem + 128 * 72;    // [128][72]
  u16* Cs = smem;               // [128][152] during epilogue (aliases As|Bs)

  // bijective XCD-chunked swizzle: 11760 = 8 * 1470; nt fastest within chunk
  const int bid0 = blockIdx.x;
  const int lin = (bid0 & 7) * 1470 + (bid0 >> 3);
  const int mt = lin / 15;
  const int nt = lin - mt * 15;

  const bool isx2 = nt >= 9;
  const float* __restrict__ X = isx2 ? x2 : x1;
  const int colbase = isx2 ? 384 + (nt - 9) * 128 : nt * 128;
  const int m0 = mt * 128;
  const int tid = threadIdx.x;
  const int lane = tid & 63, wv = tid >> 6;
  const int wr = wv >> 1, wc = wv & 1;
  const int l15 = lane & 15, l4 = lane >> 4;

  f32x4 acc[4][4] = {};

  const int ar = tid >> 1;
  const int ak = (tid & 1) * 32;
  const float* xg = X + (size_t)(m0 + ar) * CH + ak;
  const u16* bg = wT + (size_t)(colbase + ar) * CH + ak;
  u16* asw = &As[ar * 72 + ak];
  u16* bsw = &Bs[ar * 72 + ak];

  for (int kk = 0; kk < CH; kk += 64) {
    float4 av[8];
#pragma unroll
    for (int u = 0; u < 8; ++u)
      av[u] = *reinterpret_cast<const float4*>(xg + kk + u * 4);
    uint4 bv[4];
#pragma unroll
    for (int u = 0; u < 4; ++u)
      bv[u] = *reinterpret_cast<const uint4*>(bg + kk + u * 8);
    __syncthreads();
#pragma unroll
    for (int u = 0; u < 8; ++u) {
      uint2 p;
      p.x = pk2(av[u].x, av[u].y);
      p.y = pk2(av[u].z, av[u].w);
      *reinterpret_cast<uint2*>(asw + u * 4) = p;
    }
#pragma unroll
    for (int u = 0; u < 4; ++u)
      *reinterpret_cast<uint4*>(bsw + u * 8) = bv[u];
    __syncthreads();
#pragma unroll
    for (int ks = 0; ks < 2; ++ks) {
      short8 af[4], bfr[4];
#pragma unroll
      for (int i = 0; i < 4; ++i)
        af[i] = *reinterpret_cast<const short8*>(&As[(wr * 64 + i * 16 + l15) * 72 + ks * 32 + l4 * 8]);
#pragma unroll
      for (int j = 0; j < 4; ++j)
        bfr[j] = *reinterpret_cast<const short8*>(&Bs[(wc * 64 + j * 16 + l15) * 72 + ks * 32 + l4 * 8]);
#pragma unroll
      for (int i = 0; i < 4; ++i)
#pragma unroll
        for (int j = 0; j < 4; ++j)
          acc[i][j] = __builtin_amdgcn_mfma_f32_16x16x32_bf16(af[i], bfr[j], acc[i][j], 0, 0, 0);
    }
  }

  // ---- epilogue: bias+scale+pack into LDS, then coalesced 16B writes ----
  __syncthreads();
#pragma unroll
  for (int j = 0; j < 4; ++j) {
    const int colL = wc * 64 + j * 16 + l15;
    const int gcol = colbase + colL;
    const float bb = bias[gcol];
    const float scl = (gcol < 384) ? SCALE_Q : 1.0f;
#pragma unroll
    for (int i = 0; i < 4; ++i)
#pragma unroll
      for (int r = 0; r < 4; ++r) {
        const int row = wr * 64 + i * 16 + l4 * 4 + r;
        Cs[row * 152 + (colL ^ (((row >> 2) & 3) << 3))] = f2bf((acc[i][j][r] + bb) * scl);
      }
  }
  __syncthreads();

  u16* dst;
  int tb;
  if (colbase < 384)      { dst = q1;              tb = colbase; }
  else if (colbase < 768) { dst = isx2 ? k2 : k1;  tb = colbase - 384; }
  else                    { dst = isx2 ? v2 : v1;  tb = colbase - 768; }

#pragma unroll
  for (int u = 0; u < 8; ++u) {
    const int pc = tid + u * 256;           // 0..2047
    const int row = pc >> 4, pp = pc & 15;
    const uint4 val = *reinterpret_cast<const uint4*>(&Cs[row * 152 + ((pp ^ ((row >> 2) & 3)) << 3)]);
    const int gm = m0 + row;
    const int b = gm / 49, tok = gm - b * 49;
    const int cm = tb + pp * 8;
    const int h = cm >> 5, d0 = cm & 31;
    *reinterpret_cast<uint4*>(&dst[(((size_t)b * NH + h) * NTOK + tok) * HD + d0]) = val;
  }
}

// ---------- attention: one block per (b,h), 4 waves, MFMA ----------
__global__ __launch_bounds__(256) void attn_kernel(
    const u16* __restrict__ q1, const u16* __restrict__ k1, const u16* __restrict__ v1,
    const u16* __restrict__ k2, const u16* __restrict__ v2,
    const float* __restrict__ mask1, const float* __restrict__ mask2,
    const float* __restrict__ rpb, float* __restrict__ outw)
{
  __shared__ __align__(16) u16 VT[2][32][72];  // [half][d][j], j padded to 64 (49.. zeroed)
  __shared__ __align__(16) u16 Pl[64][72];     // [i][j], wave-private row stripes

  const int h = blockIdx.x, b = blockIdx.y;
  const int tid = threadIdx.x;
  const int lane = tid & 63, mt = tid >> 6;
  const int l15 = lane & 15, l4 = lane >> 4;
  const size_t base = ((size_t)b * NH + h) * 1568;

  // stage V with in-LDS transpose: v is [tok][d] contiguous per (b,h)
  for (int e = tid; e < 1568; e += 256) {
    int tok = e >> 5, d = e & 31;
    VT[0][d][tok] = v1[base + e];
    VT[1][d][tok] = v2[base + e];
  }
  // zero pad columns 49..63
  for (int e = tid; e < 2 * 32 * 15; e += 256) {
    int p = (e >= 480) ? 1 : 0;
    int e2 = e - p * 480;
    int d = e2 / 15, j = 49 + (e2 - d * 15);
    VT[p][d][j] = 0;
  }

  const short8 aq = *reinterpret_cast<const short8*>(&q1[base + (mt * 16 + l15) * 32 + l4 * 8]);

  __syncthreads();

  const int wb = b & 63;
  const float* rp = rpb + h * 2401;
  const size_t obase = (size_t)b * (NTOK * 768) + (size_t)h * 32;

#pragma unroll
  for (int p = 0; p < 2; ++p) {
    const u16* __restrict__ kp = p ? k2 : k1;
    const float* __restrict__ msk = (p ? mask2 : mask1) + (size_t)wb * 2401;

    f32x4 s[4];
#pragma unroll
    for (int n = 0; n < 4; ++n) {
      short8 bk = *reinterpret_cast<const short8*>(&kp[base + (n * 16 + l15) * 32 + l4 * 8]);
      s[n] = __builtin_amdgcn_mfma_f32_16x16x32_bf16(aq, bk, (f32x4){0.f, 0.f, 0.f, 0.f}, 0, 0, 0);
    }

#pragma unroll
    for (int r = 0; r < 4; ++r) {
      const int i = mt * 16 + l4 * 4 + r;
#pragma unroll
      for (int n = 0; n < 4; ++n) {
        const int j = n * 16 + l15;
        float v = s[n][r];
        if (j < 49) { if (i < 49) v += rp[i * 49 + j] + msk[i * 49 + j]; }
        else v = -1e30f;
        s[n][r] = v;
      }
    }

#pragma unroll
    for (int r = 0; r < 4; ++r) {
      float mx = fmaxf(fmaxf(s[0][r], s[1][r]), fmaxf(s[2][r], s[3][r]));
      mx = fmaxf(mx, __shfl_xor(mx, 1));
      mx = fmaxf(mx, __shfl_xor(mx, 2));
      mx = fmaxf(mx, __shfl_xor(mx, 4));
      mx = fmaxf(mx, __shfl_xor(mx, 8));
      float e0 = __expf(s[0][r] - mx), e1 = __expf(s[1][r] - mx);
      float e2 = __expf(s[2][r] - mx), e3 = __expf(s[3][r] - mx);
      float sm = (e0 + e1) + (e2 + e3);
      sm += __shfl_xor(sm, 1);
      sm += __shfl_xor(sm, 2);
      sm += __shfl_xor(sm, 4);
      sm += __shfl_xor(sm, 8);
      const float si = 1.f / sm;
      s[0][r] = e0 * si; s[1][r] = e1 * si; s[2][r] = e2 * si; s[3][r] = e3 * si;
    }

#pragma unroll
    for (int n = 0; n < 4; ++n)
#pragma unroll
      for (int r = 0; r < 4; ++r)
        Pl[mt * 16 + l4 * 4 + r][n * 16 + l15] = f2bf(s[n][r]);

    f32x4 o[2] = {};
#pragma unroll
    for (int kt = 0; kt < 2; ++kt) {
      short8 ap = *reinterpret_cast<const short8*>(&Pl[mt * 16 + l15][kt * 32 + l4 * 8]);
#pragma unroll
      for (int n2 = 0; n2 < 2; ++n2) {
        short8 bvf = *reinterpret_cast<const short8*>(&VT[p][n2 * 16 + l15][kt * 32 + l4 * 8]);
        o[n2] = __builtin_amdgcn_mfma_f32_16x16x32_bf16(ap, bvf, o[n2], 0, 0, 0);
      }
    }

#pragma unroll
    for (int n2 = 0; n2 < 2; ++n2)
#pragma unroll
      for (int r = 0; r < 4; ++r) {
        const int i = mt * 16 + l4 * 4 + r;
        if (i < 49)
          outw[obase + (size_t)i * 768 + p * 384 + n2 * 16 + l15] = o[n2][r];
      }
  }
}

// ---------- proj GEMM: weights[:, :384] @ w_proj + b_proj ----------
__global__ __launch_bounds__(256) void gemm_proj(
    const float* __restrict__ Wsrc, const u16* __restrict__ wT,
    const float* __restrict__ bias, float* __restrict__ outx)
{
  __shared__ __align__(16) u16 As[128 * 72];
  __shared__ __align__(16) u16 Bs[128 * 72];
  // bijective XCD-chunked swizzle: 2352 = 8 * 294
  const int bid0 = blockIdx.x;
  const int lin = (bid0 & 7) * 294 + (bid0 >> 3);
  const int mt = lin / 3;
  const int nt = lin - mt * 3;

  const int colbase = nt * 128;
  const int m0 = mt * 128;
  const int tid = threadIdx.x;
  const int lane = tid & 63, wv = tid >> 6;
  const int wr = wv >> 1, wc = wv & 1;
  const int l15 = lane & 15, l4 = lane >> 4;

  f32x4 acc[4][4] = {};

  const int ar = tid >> 1;
  const int ak = (tid & 1) * 32;
  const float* xg = Wsrc + (size_t)(m0 + ar) * 768 + ak;
  const u16* bg = wT + (size_t)(colbase + ar) * CH + ak;
  u16* asw = &As[ar * 72 + ak];
  u16* bsw = &Bs[ar * 72 + ak];

  for (int kk = 0; kk < CH; kk += 64) {
    float4 av[8];
#pragma unroll
    for (int u = 0; u < 8; ++u)
      av[u] = *reinterpret_cast<const float4*>(xg + kk + u * 4);
    uint4 bv[4];
#pragma unroll
    for (int u = 0; u < 4; ++u)
      bv[u] = *reinterpret_cast<const uint4*>(bg + kk + u * 8);
    __syncthreads();
#pragma unroll
    for (int u = 0; u < 8; ++u) {
      uint2 p;
      p.x = pk2(av[u].x, av[u].y);
      p.y = pk2(av[u].z, av[u].w);
      *reinterpret_cast<uint2*>(asw + u * 4) = p;
    }
#pragma unroll
    for (int u = 0; u < 4; ++u)
      *reinterpret_cast<uint4*>(bsw + u * 8) = bv[u];
    __syncthreads();
#pragma unroll
    for (int ks = 0; ks < 2; ++ks) {
      short8 af[4], bfr[4];
#pragma unroll
      for (int i = 0; i < 4; ++i)
        af[i] = *reinterpret_cast<const short8*>(&As[(wr * 64 + i * 16 + l15) * 72 + ks * 32 + l4 * 8]);
#pragma unroll
      for (int j = 0; j < 4; ++j)
        bfr[j] = *reinterpret_cast<const short8*>(&Bs[(wc * 64 + j * 16 + l15) * 72 + ks * 32 + l4 * 8]);
#pragma unroll
      for (int i = 0; i < 4; ++i)
#pragma unroll
        for (int j = 0; j < 4; ++j)
          acc[i][j] = __builtin_amdgcn_mfma_f32_16x16x32_bf16(af[i], bfr[j], acc[i][j], 0, 0, 0);
    }
  }

#pragma unroll
  for (int j = 0; j < 4; ++j) {
    const int col = colbase + wc * 64 + j * 16 + l15;
    const float bb = bias[col];
#pragma unroll
    for (int i = 0; i < 4; ++i) {
#pragma unroll
      for (int r = 0; r < 4; ++r) {
        const int gm = m0 + wr * 64 + i * 16 + l4 * 4 + r;
        outx[(size_t)gm * CH + col] = acc[i][j][r] + bb;
      }
    }
  }
}

extern "C" void kernel_launch(void* const* d_in, const int* in_sizes, int n_in,
                              void* d_out, int out_size, void* d_ws, size_t ws_size,
                              hipStream_t stream) {
  const float* x1        = (const float*)d_in[0];
  const float* x2        = (const float*)d_in[1];
  const float* mask1     = (const float*)d_in[2];
  const float* mask2     = (const float*)d_in[3];
  const float* w_qkv     = (const float*)d_in[4];
  const float* b_qkv     = (const float*)d_in[5];
  const float* w_proj    = (const float*)d_in[6];
  const float* b_proj    = (const float*)d_in[7];
  const float* rpb_table = (const float*)d_in[8];
  const int*   rel_index = (const int*)d_in[9];

  float* outx = (float*)d_out;                      // [2048,49,384] f32
  const size_t SZe = (size_t)NB * NH * NTOK * HD;   // 38,535,168 elements
  float* outw = outx + SZe;                         // [2048,49,768] f32

  // q1,k1 (bf16) live in the x-region of d_out; proj writes x last.
  u16* q1 = (u16*)d_out;
  u16* k1 = q1 + SZe;

  u16* v1 = (u16*)d_ws;
  u16* k2 = v1 + SZe;
  u16* v2 = k2 + SZe;
  u16* wqkvT  = v2 + SZe;              // [1152][384] bf16
  u16* wprojT = wqkvT + 1152 * 384;    // [384][384] bf16
  float* rpb  = (float*)(wprojT + 384 * 384);  // [12][49][49] f32

  {
    int total = 1152 * 384 + 384 * 384 + 12 * 2401;
    prep_kernel<<<(total + 255) / 256, 256, 0, stream>>>(w_qkv, w_proj, rpb_table, rel_index,
                                                         wqkvT, wprojT, rpb);
  }
  gemm_qkv<<<11760, 256, 0, stream>>>(x1, x2, wqkvT, b_qkv, q1, k1, v1, k2, v2);
  attn_kernel<<<dim3(12, 2048), 256, 0, stream>>>(q1, k1, v1, k2, v2, mask1, mask2, rpb, outw);
  gemm_proj<<<2352, 256, 0, stream>>>(outw, wprojT, b_proj, outx);
}

// Round 4
// 1124.596 us; speedup vs baseline: 2.3502x; 1.0342x over previous
//
#include <hip/hip_runtime.h>

typedef unsigned short u16;
typedef unsigned int u32;
typedef __attribute__((ext_vector_type(8))) short short8;
typedef __attribute__((ext_vector_type(4))) float f32x4;

#define NB 2048
#define NTOK 49
#define CH 384
#define NH 12
#define HD 32
#define SCALE_Q 0.17677669529663687f

__device__ __forceinline__ u16 f2bf(float f) {
  u32 u = __float_as_uint(f);
  u += 0x7fffu + ((u >> 16) & 1u);
  return (u16)(u >> 16);
}
__device__ __forceinline__ float bf2f(u16 h) { return __uint_as_float(((u32)h) << 16); }
__device__ __forceinline__ u32 pk2(float a, float b) { return (u32)f2bf(a) | ((u32)f2bf(b) << 16); }

// ---------- prep: transpose projection weights to bf16, gather rpb ----------
__global__ void prep_kernel(const float* __restrict__ w_qkv, const float* __restrict__ w_proj,
                            const float* __restrict__ rpb_table, const int* __restrict__ rel_index,
                            u16* __restrict__ wqkvT, u16* __restrict__ wprojT, float* __restrict__ rpb)
{
  int idx = blockIdx.x * 256 + threadIdx.x;
  if (idx < 1152 * 384) {
    int n = idx / 384, k = idx - n * 384;
    wqkvT[idx] = f2bf(w_qkv[(size_t)k * 1152 + n]);
  } else if (idx < 1152 * 384 + 384 * 384) {
    int i2 = idx - 1152 * 384;
    int n = i2 / 384, k = i2 - n * 384;
    wprojT[i2] = f2bf(w_proj[(size_t)k * 384 + n]);
  } else if (idx < 1152 * 384 + 384 * 384 + 12 * 2401) {
    int i3 = idx - (1152 * 384 + 384 * 384);
    int hh = i3 / 2401, r = i3 - hh * 2401;
    rpb[i3] = rpb_table[(size_t)rel_index[r] * 12 + hh];
  }
}

// ---------- QKV GEMM: [100352,384] @ [384,1152(+768)] bf16 MFMA ----------
// Pipelined: reg-prefetch 1 K-step ahead, double-buffered LDS, ONE barrier/step.
__global__ __launch_bounds__(256) void gemm_qkv(
    const float* __restrict__ x1, const float* __restrict__ x2,
    const u16* __restrict__ wT, const float* __restrict__ bias,
    u16* __restrict__ q1, u16* __restrict__ k1, u16* __restrict__ v1,
    u16* __restrict__ k2, u16* __restrict__ v2)
{
  __shared__ __align__(16) u16 smem[4 * 128 * 72];  // 73728 B: 2 x (As+Bs)
  u16* Cs = smem;                                   // epilogue alias [128][152]

  // bijective XCD-chunked swizzle: 11760 = 8 * 1470
  const int bid0 = blockIdx.x;
  const int lin = (bid0 & 7) * 1470 + (bid0 >> 3);
  const int mt = lin / 15;
  const int nt = lin - mt * 15;

  const bool isx2 = nt >= 9;
  const float* __restrict__ X = isx2 ? x2 : x1;
  const int colbase = isx2 ? 384 + (nt - 9) * 128 : nt * 128;
  const int m0 = mt * 128;
  const int tid = threadIdx.x;
  const int lane = tid & 63, wv = tid >> 6;
  const int wr = wv >> 1, wc = wv & 1;
  const int l15 = lane & 15, l4 = lane >> 4;

  f32x4 acc[4][4] = {};

  const int ar = tid >> 1;
  const int ak = (tid & 1) * 32;
  const float* xg = X + (size_t)(m0 + ar) * CH + ak;
  const u16* bg = wT + (size_t)(colbase + ar) * CH + ak;

  float4 av[8];
  uint4 bv[4];
#pragma unroll
  for (int u = 0; u < 8; ++u) av[u] = *reinterpret_cast<const float4*>(xg + u * 4);
#pragma unroll
  for (int u = 0; u < 4; ++u) bv[u] = *reinterpret_cast<const uint4*>(bg + u * 8);

#pragma unroll
  for (int k = 0; k < 6; ++k) {
    u16* As = smem + (k & 1) * (2 * 128 * 72);
    u16* Bs = As + 128 * 72;
    u16* asw = &As[ar * 72 + ak];
    u16* bsw = &Bs[ar * 72 + ak];
#pragma unroll
    for (int u = 0; u < 8; ++u) {
      uint2 p;
      p.x = pk2(av[u].x, av[u].y);
      p.y = pk2(av[u].z, av[u].w);
      *reinterpret_cast<uint2*>(asw + u * 4) = p;
    }
#pragma unroll
    for (int u = 0; u < 4; ++u)
      *reinterpret_cast<uint4*>(bsw + u * 8) = bv[u];
    if (k < 5) {
      const int kk = (k + 1) * 64;
#pragma unroll
      for (int u = 0; u < 8; ++u) av[u] = *reinterpret_cast<const float4*>(xg + kk + u * 4);
#pragma unroll
      for (int u = 0; u < 4; ++u) bv[u] = *reinterpret_cast<const uint4*>(bg + kk + u * 8);
    }
    __syncthreads();
#pragma unroll
    for (int ks = 0; ks < 2; ++ks) {
      short8 af[4], bfr[4];
#pragma unroll
      for (int i = 0; i < 4; ++i)
        af[i] = *reinterpret_cast<const short8*>(&As[(wr * 64 + i * 16 + l15) * 72 + ks * 32 + l4 * 8]);
#pragma unroll
      for (int j = 0; j < 4; ++j)
        bfr[j] = *reinterpret_cast<const short8*>(&Bs[(wc * 64 + j * 16 + l15) * 72 + ks * 32 + l4 * 8]);
#pragma unroll
      for (int i = 0; i < 4; ++i)
#pragma unroll
        for (int j = 0; j < 4; ++j)
          acc[i][j] = __builtin_amdgcn_mfma_f32_16x16x32_bf16(af[i], bfr[j], acc[i][j], 0, 0, 0);
    }
  }

  // ---- epilogue: bias+scale+pack into LDS, then coalesced 16B writes ----
  __syncthreads();
#pragma unroll
  for (int j = 0; j < 4; ++j) {
    const int colL = wc * 64 + j * 16 + l15;
    const int gcol = colbase + colL;
    const float bb = bias[gcol];
    const float scl = (gcol < 384) ? SCALE_Q : 1.0f;
#pragma unroll
    for (int i = 0; i < 4; ++i)
#pragma unroll
      for (int r = 0; r < 4; ++r) {
        const int row = wr * 64 + i * 16 + l4 * 4 + r;
        Cs[row * 152 + (colL ^ (((row >> 2) & 3) << 3))] = f2bf((acc[i][j][r] + bb) * scl);
      }
  }
  __syncthreads();

  u16* dst;
  int tb;
  if (colbase < 384)      { dst = q1;              tb = colbase; }
  else if (colbase < 768) { dst = isx2 ? k2 : k1;  tb = colbase - 384; }
  else                    { dst = isx2 ? v2 : v1;  tb = colbase - 768; }

#pragma unroll
  for (int u = 0; u < 8; ++u) {
    const int pc = tid + u * 256;           // 0..2047
    const int row = pc >> 4, pp = pc & 15;
    const uint4 val = *reinterpret_cast<const uint4*>(&Cs[row * 152 + ((pp ^ ((row >> 2) & 3)) << 3)]);
    const int gm = m0 + row;
    const int b = gm / 49, tok = gm - b * 49;
    const int cm = tb + pp * 8;
    const int h = cm >> 5, d0 = cm & 31;
    *reinterpret_cast<uint4*>(&dst[(((size_t)b * NH + h) * NTOK + tok) * HD + d0]) = val;
  }
}

// ---------- attention: one block per (b,h), 4 waves, MFMA ----------
__global__ __launch_bounds__(256) void attn_kernel(
    const u16* __restrict__ q1, const u16* __restrict__ k1, const u16* __restrict__ v1,
    const u16* __restrict__ k2, const u16* __restrict__ v2,
    const float* __restrict__ mask1, const float* __restrict__ mask2,
    const float* __restrict__ rpb, float* __restrict__ outw)
{
  __shared__ __align__(16) u16 VT[2][32][72];  // [half][d][j], j padded to 64 (49.. zeroed)
  __shared__ __align__(16) u16 Pl[64][72];     // [i][j], wave-private row stripes

  const int h = blockIdx.x, b = blockIdx.y;
  const int tid = threadIdx.x;
  const int lane = tid & 63, mt = tid >> 6;
  const int l15 = lane & 15, l4 = lane >> 4;
  const size_t base = ((size_t)b * NH + h) * 1568;

  // stage V with in-LDS transpose: v is [tok][d] contiguous per (b,h)
  for (int e = tid; e < 1568; e += 256) {
    int tok = e >> 5, d = e & 31;
    VT[0][d][tok] = v1[base + e];
    VT[1][d][tok] = v2[base + e];
  }
  // zero pad columns 49..63
  for (int e = tid; e < 2 * 32 * 15; e += 256) {
    int p = (e >= 480) ? 1 : 0;
    int e2 = e - p * 480;
    int d = e2 / 15, j = 49 + (e2 - d * 15);
    VT[p][d][j] = 0;
  }

  const short8 aq = *reinterpret_cast<const short8*>(&q1[base + (mt * 16 + l15) * 32 + l4 * 8]);

  __syncthreads();

  const int wb = b & 63;
  const float* rp = rpb + h * 2401;
  const size_t obase = (size_t)b * (NTOK * 768) + (size_t)h * 32;

#pragma unroll
  for (int p = 0; p < 2; ++p) {
    const u16* __restrict__ kp = p ? k2 : k1;
    const float* __restrict__ msk = (p ? mask2 : mask1) + (size_t)wb * 2401;

    f32x4 s[4];
#pragma unroll
    for (int n = 0; n < 4; ++n) {
      short8 bk = *reinterpret_cast<const short8*>(&kp[base + (n * 16 + l15) * 32 + l4 * 8]);
      s[n] = __builtin_amdgcn_mfma_f32_16x16x32_bf16(aq, bk, (f32x4){0.f, 0.f, 0.f, 0.f}, 0, 0, 0);
    }

#pragma unroll
    for (int r = 0; r < 4; ++r) {
      const int i = mt * 16 + l4 * 4 + r;
#pragma unroll
      for (int n = 0; n < 4; ++n) {
        const int j = n * 16 + l15;
        float v = s[n][r];
        if (j < 49) { if (i < 49) v += rp[i * 49 + j] + msk[i * 49 + j]; }
        else v = -1e30f;
        s[n][r] = v;
      }
    }

#pragma unroll
    for (int r = 0; r < 4; ++r) {
      float mx = fmaxf(fmaxf(s[0][r], s[1][r]), fmaxf(s[2][r], s[3][r]));
      mx = fmaxf(mx, __shfl_xor(mx, 1));
      mx = fmaxf(mx, __shfl_xor(mx, 2));
      mx = fmaxf(mx, __shfl_xor(mx, 4));
      mx = fmaxf(mx, __shfl_xor(mx, 8));
      float e0 = __expf(s[0][r] - mx), e1 = __expf(s[1][r] - mx);
      float e2 = __expf(s[2][r] - mx), e3 = __expf(s[3][r] - mx);
      float sm = (e0 + e1) + (e2 + e3);
      sm += __shfl_xor(sm, 1);
      sm += __shfl_xor(sm, 2);
      sm += __shfl_xor(sm, 4);
      sm += __shfl_xor(sm, 8);
      const float si = 1.f / sm;
      s[0][r] = e0 * si; s[1][r] = e1 * si; s[2][r] = e2 * si; s[3][r] = e3 * si;
    }

#pragma unroll
    for (int n = 0; n < 4; ++n)
#pragma unroll
      for (int r = 0; r < 4; ++r)
        Pl[mt * 16 + l4 * 4 + r][n * 16 + l15] = f2bf(s[n][r]);

    f32x4 o[2] = {};
#pragma unroll
    for (int kt = 0; kt < 2; ++kt) {
      short8 ap = *reinterpret_cast<const short8*>(&Pl[mt * 16 + l15][kt * 32 + l4 * 8]);
#pragma unroll
      for (int n2 = 0; n2 < 2; ++n2) {
        short8 bvf = *reinterpret_cast<const short8*>(&VT[p][n2 * 16 + l15][kt * 32 + l4 * 8]);
        o[n2] = __builtin_amdgcn_mfma_f32_16x16x32_bf16(ap, bvf, o[n2], 0, 0, 0);
      }
    }

#pragma unroll
    for (int n2 = 0; n2 < 2; ++n2)
#pragma unroll
      for (int r = 0; r < 4; ++r) {
        const int i = mt * 16 + l4 * 4 + r;
        if (i < 49)
          outw[obase + (size_t)i * 768 + p * 384 + n2 * 16 + l15] = o[n2][r];
      }
  }
}

// ---------- proj GEMM: weights[:, :384] @ w_proj + b_proj ----------
__global__ __launch_bounds__(256) void gemm_proj(
    const float* __restrict__ Wsrc, const u16* __restrict__ wT,
    const float* __restrict__ bias, float* __restrict__ outx)
{
  __shared__ __align__(16) u16 smem[4 * 128 * 72];  // 2 x (As+Bs)
  // bijective XCD-chunked swizzle: 2352 = 8 * 294
  const int bid0 = blockIdx.x;
  const int lin = (bid0 & 7) * 294 + (bid0 >> 3);
  const int mt = lin / 3;
  const int nt = lin - mt * 3;

  const int colbase = nt * 128;
  const int m0 = mt * 128;
  const int tid = threadIdx.x;
  const int lane = tid & 63, wv = tid >> 6;
  const int wr = wv >> 1, wc = wv & 1;
  const int l15 = lane & 15, l4 = lane >> 4;

  f32x4 acc[4][4] = {};

  const int ar = tid >> 1;
  const int ak = (tid & 1) * 32;
  const float* xg = Wsrc + (size_t)(m0 + ar) * 768 + ak;
  const u16* bg = wT + (size_t)(colbase + ar) * CH + ak;

  float4 av[8];
  uint4 bv[4];
#pragma unroll
  for (int u = 0; u < 8; ++u) av[u] = *reinterpret_cast<const float4*>(xg + u * 4);
#pragma unroll
  for (int u = 0; u < 4; ++u) bv[u] = *reinterpret_cast<const uint4*>(bg + u * 8);

#pragma unroll
  for (int k = 0; k < 6; ++k) {
    u16* As = smem + (k & 1) * (2 * 128 * 72);
    u16* Bs = As + 128 * 72;
    u16* asw = &As[ar * 72 + ak];
    u16* bsw = &Bs[ar * 72 + ak];
#pragma unroll
    for (int u = 0; u < 8; ++u) {
      uint2 p;
      p.x = pk2(av[u].x, av[u].y);
      p.y = pk2(av[u].z, av[u].w);
      *reinterpret_cast<uint2*>(asw + u * 4) = p;
    }
#pragma unroll
    for (int u = 0; u < 4; ++u)
      *reinterpret_cast<uint4*>(bsw + u * 8) = bv[u];
    if (k < 5) {
      const int kk = (k + 1) * 64;
#pragma unroll
      for (int u = 0; u < 8; ++u) av[u] = *reinterpret_cast<const float4*>(xg + kk + u * 4);
#pragma unroll
      for (int u = 0; u < 4; ++u) bv[u] = *reinterpret_cast<const uint4*>(bg + kk + u * 8);
    }
    __syncthreads();
#pragma unroll
    for (int ks = 0; ks < 2; ++ks) {
      short8 af[4], bfr[4];
#pragma unroll
      for (int i = 0; i < 4; ++i)
        af[i] = *reinterpret_cast<const short8*>(&As[(wr * 64 + i * 16 + l15) * 72 + ks * 32 + l4 * 8]);
#pragma unroll
      for (int j = 0; j < 4; ++j)
        bfr[j] = *reinterpret_cast<const short8*>(&Bs[(wc * 64 + j * 16 + l15) * 72 + ks * 32 + l4 * 8]);
#pragma unroll
      for (int i = 0; i < 4; ++i)
#pragma unroll
        for (int j = 0; j < 4; ++j)
          acc[i][j] = __builtin_amdgcn_mfma_f32_16x16x32_bf16(af[i], bfr[j], acc[i][j], 0, 0, 0);
    }
  }

#pragma unroll
  for (int j = 0; j < 4; ++j) {
    const int col = colbase + wc * 64 + j * 16 + l15;
    const float bb = bias[col];
#pragma unroll
    for (int i = 0; i < 4; ++i) {
#pragma unroll
      for (int r = 0; r < 4; ++r) {
        const int gm = m0 + wr * 64 + i * 16 + l4 * 4 + r;
        outx[(size_t)gm * CH + col] = acc[i][j][r] + bb;
      }
    }
  }
}

extern "C" void kernel_launch(void* const* d_in, const int* in_sizes, int n_in,
                              void* d_out, int out_size, void* d_ws, size_t ws_size,
                              hipStream_t stream) {
  const float* x1        = (const float*)d_in[0];
  const float* x2        = (const float*)d_in[1];
  const float* mask1     = (const float*)d_in[2];
  const float* mask2     = (const float*)d_in[3];
  const float* w_qkv     = (const float*)d_in[4];
  const float* b_qkv     = (const float*)d_in[5];
  const float* w_proj    = (const float*)d_in[6];
  const float* b_proj    = (const float*)d_in[7];
  const float* rpb_table = (const float*)d_in[8];
  const int*   rel_index = (const int*)d_in[9];

  float* outx = (float*)d_out;                      // [2048,49,384] f32
  const size_t SZe = (size_t)NB * NH * NTOK * HD;   // 38,535,168 elements
  float* outw = outx + SZe;                         // [2048,49,768] f32

  // q1,k1 (bf16) live in the x-region of d_out; proj writes x last.
  u16* q1 = (u16*)d_out;
  u16* k1 = q1 + SZe;

  u16* v1 = (u16*)d_ws;
  u16* k2 = v1 + SZe;
  u16* v2 = k2 + SZe;
  u16* wqkvT  = v2 + SZe;              // [1152][384] bf16
  u16* wprojT = wqkvT + 1152 * 384;    // [384][384] bf16
  float* rpb  = (float*)(wprojT + 384 * 384);  // [12][49][49] f32

  {
    int total = 1152 * 384 + 384 * 384 + 12 * 2401;
    prep_kernel<<<(total + 255) / 256, 256, 0, stream>>>(w_qkv, w_proj, rpb_table, rel_index,
                                                         wqkvT, wprojT, rpb);
  }
  gemm_qkv<<<11760, 256, 0, stream>>>(x1, x2, wqkvT, b_qkv, q1, k1, v1, k2, v2);
  attn_kernel<<<dim3(12, 2048), 256, 0, stream>>>(q1, k1, v1, k2, v2, mask1, mask2, rpb, outw);
  gemm_proj<<<2352, 256, 0, stream>>>(outw, wprojT, b_proj, outx);
}

// Round 5
// 938.230 us; speedup vs baseline: 2.8170x; 1.1986x over previous
//
#include <hip/hip_runtime.h>

typedef unsigned short u16;
typedef unsigned int u32;
typedef __attribute__((ext_vector_type(8))) short short8;
typedef __attribute__((ext_vector_type(4))) float f32x4;

#define NB 2048
#define NTOK 49
#define CH 384
#define NH 12
#define HD 32
#define SCALE_Q 0.17677669529663687f

__device__ __forceinline__ u16 f2bf(float f) {
  u32 u = __float_as_uint(f);
  u += 0x7fffu + ((u >> 16) & 1u);
  return (u16)(u >> 16);
}
__device__ __forceinline__ float bf2f(u16 h) { return __uint_as_float(((u32)h) << 16); }
__device__ __forceinline__ u32 pk2(float a, float b) { return (u32)f2bf(a) | ((u32)f2bf(b) << 16); }

// async global->LDS, 16B per lane, LDS dest = wave-uniform base + lane*16
__device__ __forceinline__ void gload16(const u16* g, u16* l) {
  __builtin_amdgcn_global_load_lds(
      (const __attribute__((address_space(1))) u32*)g,
      (__attribute__((address_space(3))) u32*)l,
      16, 0, 0);
}

// ---------- prep: transpose weights to bf16, gather rpb ----------
__global__ void prep_kernel(const float* __restrict__ w_qkv, const float* __restrict__ w_proj,
                            const float* __restrict__ rpb_table, const int* __restrict__ rel_index,
                            u16* __restrict__ wqkvT, u16* __restrict__ wprojT, float* __restrict__ rpb)
{
  int idx = blockIdx.x * 256 + threadIdx.x;
  if (idx < 1152 * 384) {
    int n = idx / 384, k = idx - n * 384;
    wqkvT[idx] = f2bf(w_qkv[(size_t)k * 1152 + n]);
  } else if (idx < 1152 * 384 + 384 * 384) {
    int i2 = idx - 1152 * 384;
    int n = i2 / 384, k = i2 - n * 384;
    wprojT[i2] = f2bf(w_proj[(size_t)k * 384 + n]);
  } else if (idx < 1152 * 384 + 384 * 384 + 12 * 2401) {
    int i3 = idx - (1152 * 384 + 384 * 384);
    int hh = i3 / 2401, r = i3 - hh * 2401;
    rpb[i3] = rpb_table[(size_t)rel_index[r] * 12 + hh];
  }
}

// ---------- convert x1,x2 f32 -> bf16 (8 elems/thread) ----------
__global__ __launch_bounds__(256) void conv_bf16(const float* __restrict__ x1, const float* __restrict__ x2,
                                                 u16* __restrict__ xb1, u16* __restrict__ xb2)
{
  const size_t i = ((size_t)blockIdx.x * 256 + threadIdx.x) * 8;
  float4 a = *reinterpret_cast<const float4*>(x1 + i);
  float4 b = *reinterpret_cast<const float4*>(x1 + i + 4);
  uint4 o;
  o.x = pk2(a.x, a.y); o.y = pk2(a.z, a.w); o.z = pk2(b.x, b.y); o.w = pk2(b.z, b.w);
  *reinterpret_cast<uint4*>(xb1 + i) = o;
  a = *reinterpret_cast<const float4*>(x2 + i);
  b = *reinterpret_cast<const float4*>(x2 + i + 4);
  o.x = pk2(a.x, a.y); o.y = pk2(a.z, a.w); o.z = pk2(b.x, b.y); o.w = pk2(b.z, b.w);
  *reinterpret_cast<uint4*>(xb2 + i) = o;
}

// ---------- QKV GEMM: [100352,384]bf16 @ [384,1152(+768)]bf16 MFMA ----------
// global_load_lds staging into operand-order LDS blocks (16 x 1KB per tile):
// block g=(rowgrp i)*2+ks holds A[i*16+l15][kk+ks*32+l4*8..+7] at lane l4*16+l15.
// Fragment ds_read_b128 = contiguous 1KB wave read (conflict-free).
__global__ __launch_bounds__(256) void gemm_qkv(
    const u16* __restrict__ xb1, const u16* __restrict__ xb2,
    const u16* __restrict__ wT, const float* __restrict__ bias,
    u16* __restrict__ q1, u16* __restrict__ k1, u16* __restrict__ v1,
    u16* __restrict__ k2, u16* __restrict__ v2)
{
  __shared__ __align__(16) u16 smem[2][2][8192];  // [buf][A/B][16 blocks x 512] = 64KB
  u16* Cs = &smem[0][0][0];                       // epilogue alias [128][152] = 38912B

  // bijective XCD-chunked swizzle: 11760 = 8 * 1470
  const int bid0 = blockIdx.x;
  const int lin = (bid0 & 7) * 1470 + (bid0 >> 3);
  const int mt = lin / 15;
  const int nt = lin - mt * 15;

  const bool isx2 = nt >= 9;
  const u16* __restrict__ X = isx2 ? xb2 : xb1;
  const int colbase = isx2 ? 384 + (nt - 9) * 128 : nt * 128;
  const int m0 = mt * 128;
  const int tid = threadIdx.x;
  const int lane = tid & 63, wv = tid >> 6;
  const int wr = wv >> 1, wc = wv & 1;
  const int l15 = lane & 15, l4 = lane >> 4;

  f32x4 acc[4][4] = {};

  // per-lane global base: row (m0|colbase)+l15, col l4*8
  const u16* ga = X + (size_t)(m0 + l15) * CH + l4 * 8;
  const u16* gb = wT + (size_t)(colbase + l15) * CH + l4 * 8;
  int goff[4];
#pragma unroll
  for (int u = 0; u < 4; ++u) {
    const int g = u * 4 + wv, i = g >> 1, ks = g & 1;
    goff[u] = i * 16 * CH + ks * 32;
  }

  auto stage = [&](int bs, int kk) {
#pragma unroll
    for (int u = 0; u < 4; ++u) {
      const int g = u * 4 + wv;
      gload16(ga + kk + goff[u], &smem[bs][0][g * 512]);
      gload16(gb + kk + goff[u], &smem[bs][1][g * 512]);
    }
  };

  stage(0, 0);
  __syncthreads();  // barrier drains vmcnt(0): buf0 ready

  int cur = 0;
#pragma unroll
  for (int k = 0; k < 6; ++k) {
    if (k < 5) stage(cur ^ 1, (k + 1) * 64);   // loads in flight across the MFMA cluster
#pragma unroll
    for (int ks = 0; ks < 2; ++ks) {
      short8 af[4], bfr[4];
#pragma unroll
      for (int i = 0; i < 4; ++i)
        af[i] = *reinterpret_cast<const short8*>(&smem[cur][0][((wr * 4 + i) * 2 + ks) * 512 + lane * 8]);
#pragma unroll
      for (int j = 0; j < 4; ++j)
        bfr[j] = *reinterpret_cast<const short8*>(&smem[cur][1][((wc * 4 + j) * 2 + ks) * 512 + lane * 8]);
#pragma unroll
      for (int i = 0; i < 4; ++i)
#pragma unroll
        for (int j = 0; j < 4; ++j)
          acc[i][j] = __builtin_amdgcn_mfma_f32_16x16x32_bf16(af[i], bfr[j], acc[i][j], 0, 0, 0);
    }
    __syncthreads();  // drains this step's stage loads; next iter may overwrite buf[cur]
    cur ^= 1;
  }

  // ---- epilogue: bias+scale+pack into LDS, then coalesced 16B writes ----
#pragma unroll
  for (int j = 0; j < 4; ++j) {
    const int colL = wc * 64 + j * 16 + l15;
    const int gcol = colbase + colL;
    const float bb = bias[gcol];
    const float scl = (gcol < 384) ? SCALE_Q : 1.0f;
#pragma unroll
    for (int i = 0; i < 4; ++i)
#pragma unroll
      for (int r = 0; r < 4; ++r) {
        const int row = wr * 64 + i * 16 + l4 * 4 + r;
        Cs[row * 152 + (colL ^ (((row >> 2) & 3) << 3))] = f2bf((acc[i][j][r] + bb) * scl);
      }
  }
  __syncthreads();

  u16* dst;
  int tb;
  if (colbase < 384)      { dst = q1;              tb = colbase; }
  else if (colbase < 768) { dst = isx2 ? k2 : k1;  tb = colbase - 384; }
  else                    { dst = isx2 ? v2 : v1;  tb = colbase - 768; }

#pragma unroll
  for (int u = 0; u < 8; ++u) {
    const int pc = tid + u * 256;           // 0..2047
    const int row = pc >> 4, pp = pc & 15;
    const uint4 val = *reinterpret_cast<const uint4*>(&Cs[row * 152 + ((pp ^ ((row >> 2) & 3)) << 3)]);
    const int gm = m0 + row;
    const int b = gm / 49, tok = gm - b * 49;
    const int cm = tb + pp * 8;
    const int h = cm >> 5, d0 = cm & 31;
    *reinterpret_cast<uint4*>(&dst[(((size_t)b * NH + h) * NTOK + tok) * HD + d0]) = val;
  }
}

// ---------- attention: one block per (b,h), 4 waves, MFMA ----------
__global__ __launch_bounds__(256) void attn_kernel(
    const u16* __restrict__ q1, const u16* __restrict__ k1, const u16* __restrict__ v1,
    const u16* __restrict__ k2, const u16* __restrict__ v2,
    const float* __restrict__ mask1, const float* __restrict__ mask2,
    const float* __restrict__ rpb, float* __restrict__ outw)
{
  __shared__ __align__(16) u16 VT[2][32][72];  // [half][d][j], j padded to 64 (49.. zeroed)
  __shared__ __align__(16) u16 Pl[64][72];     // [i][j], wave-private row stripes

  const int h = blockIdx.x, b = blockIdx.y;
  const int tid = threadIdx.x;
  const int lane = tid & 63, mt = tid >> 6;
  const int l15 = lane & 15, l4 = lane >> 4;
  const size_t base = ((size_t)b * NH + h) * 1568;

  // stage V with in-LDS transpose: v is [tok][d] contiguous per (b,h)
  for (int e = tid; e < 1568; e += 256) {
    int tok = e >> 5, d = e & 31;
    VT[0][d][tok] = v1[base + e];
    VT[1][d][tok] = v2[base + e];
  }
  // zero pad columns 49..63
  for (int e = tid; e < 2 * 32 * 15; e += 256) {
    int p = (e >= 480) ? 1 : 0;
    int e2 = e - p * 480;
    int d = e2 / 15, j = 49 + (e2 - d * 15);
    VT[p][d][j] = 0;
  }

  const short8 aq = *reinterpret_cast<const short8*>(&q1[base + (mt * 16 + l15) * 32 + l4 * 8]);

  __syncthreads();

  const int wb = b & 63;
  const float* rp = rpb + h * 2401;
  const size_t obase = (size_t)b * (NTOK * 768) + (size_t)h * 32;

#pragma unroll
  for (int p = 0; p < 2; ++p) {
    const u16* __restrict__ kp = p ? k2 : k1;
    const float* __restrict__ msk = (p ? mask2 : mask1) + (size_t)wb * 2401;

    f32x4 s[4];
#pragma unroll
    for (int n = 0; n < 4; ++n) {
      short8 bk = *reinterpret_cast<const short8*>(&kp[base + (n * 16 + l15) * 32 + l4 * 8]);
      s[n] = __builtin_amdgcn_mfma_f32_16x16x32_bf16(aq, bk, (f32x4){0.f, 0.f, 0.f, 0.f}, 0, 0, 0);
    }

#pragma unroll
    for (int r = 0; r < 4; ++r) {
      const int i = mt * 16 + l4 * 4 + r;
#pragma unroll
      for (int n = 0; n < 4; ++n) {
        const int j = n * 16 + l15;
        float v = s[n][r];
        if (j < 49) { if (i < 49) v += rp[i * 49 + j] + msk[i * 49 + j]; }
        else v = -1e30f;
        s[n][r] = v;
      }
    }

#pragma unroll
    for (int r = 0; r < 4; ++r) {
      float mx = fmaxf(fmaxf(s[0][r], s[1][r]), fmaxf(s[2][r], s[3][r]));
      mx = fmaxf(mx, __shfl_xor(mx, 1));
      mx = fmaxf(mx, __shfl_xor(mx, 2));
      mx = fmaxf(mx, __shfl_xor(mx, 4));
      mx = fmaxf(mx, __shfl_xor(mx, 8));
      float e0 = __expf(s[0][r] - mx), e1 = __expf(s[1][r] - mx);
      float e2 = __expf(s[2][r] - mx), e3 = __expf(s[3][r] - mx);
      float sm = (e0 + e1) + (e2 + e3);
      sm += __shfl_xor(sm, 1);
      sm += __shfl_xor(sm, 2);
      sm += __shfl_xor(sm, 4);
      sm += __shfl_xor(sm, 8);
      const float si = 1.f / sm;
      s[0][r] = e0 * si; s[1][r] = e1 * si; s[2][r] = e2 * si; s[3][r] = e3 * si;
    }

#pragma unroll
    for (int n = 0; n < 4; ++n)
#pragma unroll
      for (int r = 0; r < 4; ++r)
        Pl[mt * 16 + l4 * 4 + r][n * 16 + l15] = f2bf(s[n][r]);

    f32x4 o[2] = {};
#pragma unroll
    for (int kt = 0; kt < 2; ++kt) {
      short8 ap = *reinterpret_cast<const short8*>(&Pl[mt * 16 + l15][kt * 32 + l4 * 8]);
#pragma unroll
      for (int n2 = 0; n2 < 2; ++n2) {
        short8 bvf = *reinterpret_cast<const short8*>(&VT[p][n2 * 16 + l15][kt * 32 + l4 * 8]);
        o[n2] = __builtin_amdgcn_mfma_f32_16x16x32_bf16(ap, bvf, o[n2], 0, 0, 0);
      }
    }

#pragma unroll
    for (int n2 = 0; n2 < 2; ++n2)
#pragma unroll
      for (int r = 0; r < 4; ++r) {
        const int i = mt * 16 + l4 * 4 + r;
        if (i < 49)
          outw[obase + (size_t)i * 768 + p * 384 + n2 * 16 + l15] = o[n2][r];
      }
  }
}

// ---------- proj GEMM: weights[:, :384] @ w_proj + b_proj ----------
__global__ __launch_bounds__(256) void gemm_proj(
    const float* __restrict__ Wsrc, const u16* __restrict__ wT,
    const float* __restrict__ bias, float* __restrict__ outx)
{
  __shared__ __align__(16) u16 smem[4 * 128 * 72];  // 2 x (As+Bs)
  // bijective XCD-chunked swizzle: 2352 = 8 * 294
  const int bid0 = blockIdx.x;
  const int lin = (bid0 & 7) * 294 + (bid0 >> 3);
  const int mt = lin / 3;
  const int nt = lin - mt * 3;

  const int colbase = nt * 128;
  const int m0 = mt * 128;
  const int tid = threadIdx.x;
  const int lane = tid & 63, wv = tid >> 6;
  const int wr = wv >> 1, wc = wv & 1;
  const int l15 = lane & 15, l4 = lane >> 4;

  f32x4 acc[4][4] = {};

  const int ar = tid >> 1;
  const int ak = (tid & 1) * 32;
  const float* xg = Wsrc + (size_t)(m0 + ar) * 768 + ak;
  const u16* bg = wT + (size_t)(colbase + ar) * CH + ak;

  float4 av[8];
  uint4 bv[4];
#pragma unroll
  for (int u = 0; u < 8; ++u) av[u] = *reinterpret_cast<const float4*>(xg + u * 4);
#pragma unroll
  for (int u = 0; u < 4; ++u) bv[u] = *reinterpret_cast<const uint4*>(bg + u * 8);

#pragma unroll
  for (int k = 0; k < 6; ++k) {
    u16* As = smem + (k & 1) * (2 * 128 * 72);
    u16* Bs = As + 128 * 72;
    u16* asw = &As[ar * 72 + ak];
    u16* bsw = &Bs[ar * 72 + ak];
#pragma unroll
    for (int u = 0; u < 8; ++u) {
      uint2 p;
      p.x = pk2(av[u].x, av[u].y);
      p.y = pk2(av[u].z, av[u].w);
      *reinterpret_cast<uint2*>(asw + u * 4) = p;
    }
#pragma unroll
    for (int u = 0; u < 4; ++u)
      *reinterpret_cast<uint4*>(bsw + u * 8) = bv[u];
    if (k < 5) {
      const int kk = (k + 1) * 64;
#pragma unroll
      for (int u = 0; u < 8; ++u) av[u] = *reinterpret_cast<const float4*>(xg + kk + u * 4);
#pragma unroll
      for (int u = 0; u < 4; ++u) bv[u] = *reinterpret_cast<const uint4*>(bg + kk + u * 8);
    }
    __syncthreads();
#pragma unroll
    for (int ks = 0; ks < 2; ++ks) {
      short8 af[4], bfr[4];
#pragma unroll
      for (int i = 0; i < 4; ++i)
        af[i] = *reinterpret_cast<const short8*>(&As[(wr * 64 + i * 16 + l15) * 72 + ks * 32 + l4 * 8]);
#pragma unroll
      for (int j = 0; j < 4; ++j)
        bfr[j] = *reinterpret_cast<const short8*>(&Bs[(wc * 64 + j * 16 + l15) * 72 + ks * 32 + l4 * 8]);
#pragma unroll
      for (int i = 0; i < 4; ++i)
#pragma unroll
        for (int j = 0; j < 4; ++j)
          acc[i][j] = __builtin_amdgcn_mfma_f32_16x16x32_bf16(af[i], bfr[j], acc[i][j], 0, 0, 0);
    }
  }

#pragma unroll
  for (int j = 0; j < 4; ++j) {
    const int col = colbase + wc * 64 + j * 16 + l15;
    const float bb = bias[col];
#pragma unroll
    for (int i = 0; i < 4; ++i) {
#pragma unroll
      for (int r = 0; r < 4; ++r) {
        const int gm = m0 + wr * 64 + i * 16 + l4 * 4 + r;
        outx[(size_t)gm * CH + col] = acc[i][j][r] + bb;
      }
    }
  }
}

extern "C" void kernel_launch(void* const* d_in, const int* in_sizes, int n_in,
                              void* d_out, int out_size, void* d_ws, size_t ws_size,
                              hipStream_t stream) {
  const float* x1        = (const float*)d_in[0];
  const float* x2        = (const float*)d_in[1];
  const float* mask1     = (const float*)d_in[2];
  const float* mask2     = (const float*)d_in[3];
  const float* w_qkv     = (const float*)d_in[4];
  const float* b_qkv     = (const float*)d_in[5];
  const float* w_proj    = (const float*)d_in[6];
  const float* b_proj    = (const float*)d_in[7];
  const float* rpb_table = (const float*)d_in[8];
  const int*   rel_index = (const int*)d_in[9];

  float* outx = (float*)d_out;                      // [2048,49,384] f32
  const size_t SZe = (size_t)NB * NH * NTOK * HD;   // 38,535,168 elements
  float* outw = outx + SZe;                         // [2048,49,768] f32

  // q1,k1 (bf16) live in the x-region of d_out; proj writes x last.
  u16* q1 = (u16*)d_out;
  u16* k1 = q1 + SZe;
  // xb1,xb2 (bf16 copies of x1,x2) live in the outw region; attn overwrites later.
  u16* xb1 = (u16*)outw;
  u16* xb2 = xb1 + SZe;

  u16* v1 = (u16*)d_ws;
  u16* k2 = v1 + SZe;
  u16* v2 = k2 + SZe;
  u16* wqkvT  = v2 + SZe;              // [1152][384] bf16
  u16* wprojT = wqkvT + 1152 * 384;    // [384][384] bf16
  float* rpb  = (float*)(wprojT + 384 * 384);  // [12][49][49] f32

  {
    int total = 1152 * 384 + 384 * 384 + 12 * 2401;
    prep_kernel<<<(total + 255) / 256, 256, 0, stream>>>(w_qkv, w_proj, rpb_table, rel_index,
                                                         wqkvT, wprojT, rpb);
  }
  conv_bf16<<<(int)(SZe / (256 * 8)), 256, 0, stream>>>(x1, x2, xb1, xb2);
  gemm_qkv<<<11760, 256, 0, stream>>>(xb1, xb2, wqkvT, b_qkv, q1, k1, v1, k2, v2);
  attn_kernel<<<dim3(12, 2048), 256, 0, stream>>>(q1, k1, v1, k2, v2, mask1, mask2, rpb, outw);
  gemm_proj<<<2352, 256, 0, stream>>>(outw, wprojT, b_proj, outx);
}

// Round 6
// 851.069 us; speedup vs baseline: 3.1055x; 1.1024x over previous
//
#include <hip/hip_runtime.h>

typedef unsigned short u16;
typedef unsigned int u32;
typedef __attribute__((ext_vector_type(8))) short short8;
typedef __attribute__((ext_vector_type(4))) float f32x4;

#define NB 2048
#define NTOK 49
#define CH 384
#define NH 12
#define HD 32
#define SCALE_Q 0.17677669529663687f

__device__ __forceinline__ u16 f2bf(float f) {
  u32 u = __float_as_uint(f);
  u += 0x7fffu + ((u >> 16) & 1u);
  return (u16)(u >> 16);
}
__device__ __forceinline__ float bf2f(u16 h) { return __uint_as_float(((u32)h) << 16); }
__device__ __forceinline__ u32 pk2(float a, float b) { return (u32)f2bf(a) | ((u32)f2bf(b) << 16); }

// async global->LDS, 16B per lane, LDS dest = wave-uniform base + lane*16
__device__ __forceinline__ void gload16(const u16* g, u16* l) {
  __builtin_amdgcn_global_load_lds(
      (const __attribute__((address_space(1))) u32*)g,
      (__attribute__((address_space(3))) u32*)l,
      16, 0, 0);
}

// ---------- prep: transpose weights to bf16, gather rpb ----------
__global__ void prep_kernel(const float* __restrict__ w_qkv, const float* __restrict__ w_proj,
                            const float* __restrict__ rpb_table, const int* __restrict__ rel_index,
                            u16* __restrict__ wqkvT, u16* __restrict__ wprojT, float* __restrict__ rpb)
{
  int idx = blockIdx.x * 256 + threadIdx.x;
  if (idx < 1152 * 384) {
    int n = idx / 384, k = idx - n * 384;
    wqkvT[idx] = f2bf(w_qkv[(size_t)k * 1152 + n]);
  } else if (idx < 1152 * 384 + 384 * 384) {
    int i2 = idx - 1152 * 384;
    int n = i2 / 384, k = i2 - n * 384;
    wprojT[i2] = f2bf(w_proj[(size_t)k * 384 + n]);
  } else if (idx < 1152 * 384 + 384 * 384 + 12 * 2401) {
    int i3 = idx - (1152 * 384 + 384 * 384);
    int hh = i3 / 2401, r = i3 - hh * 2401;
    rpb[i3] = rpb_table[(size_t)rel_index[r] * 12 + hh];
  }
}

// ---------- convert x1,x2 f32 -> bf16 (8 elems/thread) ----------
__global__ __launch_bounds__(256) void conv_bf16(const float* __restrict__ x1, const float* __restrict__ x2,
                                                 u16* __restrict__ xb1, u16* __restrict__ xb2)
{
  const size_t i = ((size_t)blockIdx.x * 256 + threadIdx.x) * 8;
  float4 a = *reinterpret_cast<const float4*>(x1 + i);
  float4 b = *reinterpret_cast<const float4*>(x1 + i + 4);
  uint4 o;
  o.x = pk2(a.x, a.y); o.y = pk2(a.z, a.w); o.z = pk2(b.x, b.y); o.w = pk2(b.z, b.w);
  *reinterpret_cast<uint4*>(xb1 + i) = o;
  a = *reinterpret_cast<const float4*>(x2 + i);
  b = *reinterpret_cast<const float4*>(x2 + i + 4);
  o.x = pk2(a.x, a.y); o.y = pk2(a.z, a.w); o.z = pk2(b.x, b.y); o.w = pk2(b.z, b.w);
  *reinterpret_cast<uint4*>(xb2 + i) = o;
}

// ---------- QKV GEMM: counted-vmcnt pipeline, global_load_lds staging ----------
__global__ __launch_bounds__(256) void gemm_qkv(
    const u16* __restrict__ xb1, const u16* __restrict__ xb2,
    const u16* __restrict__ wT, const float* __restrict__ bias,
    u16* __restrict__ q1, u16* __restrict__ k1, u16* __restrict__ v1,
    u16* __restrict__ k2, u16* __restrict__ v2)
{
  __shared__ __align__(16) u16 smem[2][2][8192];  // [buf][A/B][16 blocks x 512] = 64KB
  u16* Cs = &smem[0][0][0];                       // epilogue alias [128][152]

  // bijective XCD-chunked swizzle: 11760 = 8 * 1470
  const int bid0 = blockIdx.x;
  const int lin = (bid0 & 7) * 1470 + (bid0 >> 3);
  const int mt = lin / 15;
  const int nt = lin - mt * 15;

  const bool isx2 = nt >= 9;
  const u16* __restrict__ X = isx2 ? xb2 : xb1;
  const int colbase = isx2 ? 384 + (nt - 9) * 128 : nt * 128;
  const int m0 = mt * 128;
  const int tid = threadIdx.x;
  const int lane = tid & 63, wv = tid >> 6;
  const int wr = wv >> 1, wc = wv & 1;
  const int l15 = lane & 15, l4 = lane >> 4;

  f32x4 acc[4][4] = {};

  const u16* ga = X + (size_t)(m0 + l15) * CH + l4 * 8;
  const u16* gb = wT + (size_t)(colbase + l15) * CH + l4 * 8;
  int goff[4];
#pragma unroll
  for (int u = 0; u < 4; ++u) {
    const int g = u * 4 + wv, i = g >> 1, ks = g & 1;
    goff[u] = i * 16 * CH + ks * 32;
  }

  auto stage = [&](int bs, int kk) {
#pragma unroll
    for (int u = 0; u < 4; ++u) {
      const int g = u * 4 + wv;
      gload16(ga + kk + goff[u], &smem[bs][0][g * 512]);
      gload16(gb + kk + goff[u], &smem[bs][1][g * 512]);
    }
  };

  stage(0, 0);     // 8 loads
  stage(1, 64);    // 8 loads -> 16 outstanding

#pragma unroll
  for (int k = 0; k < 6; ++k) {
    if (k < 5) asm volatile("s_waitcnt vmcnt(8)" ::: "memory");   // stage(k) done, stage(k+1) in flight
    else       asm volatile("s_waitcnt vmcnt(0)" ::: "memory");
    __builtin_amdgcn_s_barrier();
    __builtin_amdgcn_sched_barrier(0);
    const int cb = k & 1;
#pragma unroll
    for (int ks = 0; ks < 2; ++ks) {
      short8 af[4], bfr[4];
#pragma unroll
      for (int i = 0; i < 4; ++i)
        af[i] = *reinterpret_cast<const short8*>(&smem[cb][0][((wr * 4 + i) * 2 + ks) * 512 + lane * 8]);
#pragma unroll
      for (int j = 0; j < 4; ++j)
        bfr[j] = *reinterpret_cast<const short8*>(&smem[cb][1][((wc * 4 + j) * 2 + ks) * 512 + lane * 8]);
#pragma unroll
      for (int i = 0; i < 4; ++i)
#pragma unroll
        for (int j = 0; j < 4; ++j)
          acc[i][j] = __builtin_amdgcn_mfma_f32_16x16x32_bf16(af[i], bfr[j], acc[i][j], 0, 0, 0);
    }
    asm volatile("s_waitcnt lgkmcnt(0)" ::: "memory");
    __builtin_amdgcn_s_barrier();
    __builtin_amdgcn_sched_barrier(0);
    if (k + 2 < 6) stage(cb, (k + 2) * 64);   // refill freed buffer; stays in flight across barriers
  }

  // ---- epilogue: bias+scale+pack into LDS, then coalesced 16B writes ----
#pragma unroll
  for (int j = 0; j < 4; ++j) {
    const int colL = wc * 64 + j * 16 + l15;
    const int gcol = colbase + colL;
    const float bb = bias[gcol];
    const float scl = (gcol < 384) ? SCALE_Q : 1.0f;
#pragma unroll
    for (int i = 0; i < 4; ++i)
#pragma unroll
      for (int r = 0; r < 4; ++r) {
        const int row = wr * 64 + i * 16 + l4 * 4 + r;
        Cs[row * 152 + (colL ^ (((row >> 2) & 3) << 3))] = f2bf((acc[i][j][r] + bb) * scl);
      }
  }
  __syncthreads();

  u16* dst;
  int tb;
  if (colbase < 384)      { dst = q1;              tb = colbase; }
  else if (colbase < 768) { dst = isx2 ? k2 : k1;  tb = colbase - 384; }
  else                    { dst = isx2 ? v2 : v1;  tb = colbase - 768; }

#pragma unroll
  for (int u = 0; u < 8; ++u) {
    const int pc = tid + u * 256;           // 0..2047
    const int row = pc >> 4, pp = pc & 15;
    const uint4 val = *reinterpret_cast<const uint4*>(&Cs[row * 152 + ((pp ^ ((row >> 2) & 3)) << 3)]);
    const int gm = m0 + row;
    const int b = gm / 49, tok = gm - b * 49;
    const int cm = tb + pp * 8;
    const int h = cm >> 5, d0 = cm & 31;
    *reinterpret_cast<uint4*>(&dst[(((size_t)b * NH + h) * NTOK + tok) * HD + d0]) = val;
  }
}

// ---------- attention: one block per (b,h), 4 waves, MFMA ----------
__global__ __launch_bounds__(256) void attn_kernel(
    const u16* __restrict__ q1, const u16* __restrict__ k1, const u16* __restrict__ v1,
    const u16* __restrict__ k2, const u16* __restrict__ v2,
    const float* __restrict__ mask1, const float* __restrict__ mask2,
    const float* __restrict__ rpb, float* __restrict__ outw)
{
  __shared__ __align__(16) u16 VT[2][32][72];  // [half][d][j], j padded to 64 (49.. zeroed)
  __shared__ __align__(16) u16 Pl[64][72];     // [i][j], wave-private row stripes

  const int h = blockIdx.x, b = blockIdx.y;
  const int tid = threadIdx.x;
  const int lane = tid & 63, mt = tid >> 6;
  const int l15 = lane & 15, l4 = lane >> 4;
  const size_t base = ((size_t)b * NH + h) * 1568;

  for (int e = tid; e < 1568; e += 256) {
    int tok = e >> 5, d = e & 31;
    VT[0][d][tok] = v1[base + e];
    VT[1][d][tok] = v2[base + e];
  }
  for (int e = tid; e < 2 * 32 * 15; e += 256) {
    int p = (e >= 480) ? 1 : 0;
    int e2 = e - p * 480;
    int d = e2 / 15, j = 49 + (e2 - d * 15);
    VT[p][d][j] = 0;
  }

  const short8 aq = *reinterpret_cast<const short8*>(&q1[base + (mt * 16 + l15) * 32 + l4 * 8]);

  __syncthreads();

  const int wb = b & 63;
  const float* rp = rpb + h * 2401;
  const size_t obase = (size_t)b * (NTOK * 768) + (size_t)h * 32;

#pragma unroll
  for (int p = 0; p < 2; ++p) {
    const u16* __restrict__ kp = p ? k2 : k1;
    const float* __restrict__ msk = (p ? mask2 : mask1) + (size_t)wb * 2401;

    f32x4 s[4];
#pragma unroll
    for (int n = 0; n < 4; ++n) {
      short8 bk = *reinterpret_cast<const short8*>(&kp[base + (n * 16 + l15) * 32 + l4 * 8]);
      s[n] = __builtin_amdgcn_mfma_f32_16x16x32_bf16(aq, bk, (f32x4){0.f, 0.f, 0.f, 0.f}, 0, 0, 0);
    }

#pragma unroll
    for (int r = 0; r < 4; ++r) {
      const int i = mt * 16 + l4 * 4 + r;
#pragma unroll
      for (int n = 0; n < 4; ++n) {
        const int j = n * 16 + l15;
        float v = s[n][r];
        if (j < 49) { if (i < 49) v += rp[i * 49 + j] + msk[i * 49 + j]; }
        else v = -1e30f;
        s[n][r] = v;
      }
    }

#pragma unroll
    for (int r = 0; r < 4; ++r) {
      float mx = fmaxf(fmaxf(s[0][r], s[1][r]), fmaxf(s[2][r], s[3][r]));
      mx = fmaxf(mx, __shfl_xor(mx, 1));
      mx = fmaxf(mx, __shfl_xor(mx, 2));
      mx = fmaxf(mx, __shfl_xor(mx, 4));
      mx = fmaxf(mx, __shfl_xor(mx, 8));
      float e0 = __expf(s[0][r] - mx), e1 = __expf(s[1][r] - mx);
      float e2 = __expf(s[2][r] - mx), e3 = __expf(s[3][r] - mx);
      float sm = (e0 + e1) + (e2 + e3);
      sm += __shfl_xor(sm, 1);
      sm += __shfl_xor(sm, 2);
      sm += __shfl_xor(sm, 4);
      sm += __shfl_xor(sm, 8);
      const float si = 1.f / sm;
      s[0][r] = e0 * si; s[1][r] = e1 * si; s[2][r] = e2 * si; s[3][r] = e3 * si;
    }

#pragma unroll
    for (int n = 0; n < 4; ++n)
#pragma unroll
      for (int r = 0; r < 4; ++r)
        Pl[mt * 16 + l4 * 4 + r][n * 16 + l15] = f2bf(s[n][r]);

    f32x4 o[2] = {};
#pragma unroll
    for (int kt = 0; kt < 2; ++kt) {
      short8 ap = *reinterpret_cast<const short8*>(&Pl[mt * 16 + l15][kt * 32 + l4 * 8]);
#pragma unroll
      for (int n2 = 0; n2 < 2; ++n2) {
        short8 bvf = *reinterpret_cast<const short8*>(&VT[p][n2 * 16 + l15][kt * 32 + l4 * 8]);
        o[n2] = __builtin_amdgcn_mfma_f32_16x16x32_bf16(ap, bvf, o[n2], 0, 0, 0);
      }
    }

#pragma unroll
    for (int n2 = 0; n2 < 2; ++n2)
#pragma unroll
      for (int r = 0; r < 4; ++r) {
        const int i = mt * 16 + l4 * 4 + r;
        if (i < 49)
          outw[obase + (size_t)i * 768 + p * 384 + n2 * 16 + l15] = o[n2][r];
      }
  }
}

// ---------- proj GEMM: counted-vmcnt pipeline; A(f32) reg-staged coalesced, B via gload_lds ----------
__global__ __launch_bounds__(256) void gemm_proj(
    const float* __restrict__ Wsrc, const u16* __restrict__ wT,
    const float* __restrict__ bias, float* __restrict__ outx)
{
  __shared__ __align__(16) u16 smem[2][2][8192];  // 64KB
  // bijective XCD-chunked swizzle: 2352 = 8 * 294
  const int bid0 = blockIdx.x;
  const int lin = (bid0 & 7) * 294 + (bid0 >> 3);
  const int mt = lin / 3;
  const int nt = lin - mt * 3;

  const int colbase = nt * 128;
  const int m0 = mt * 128;
  const int tid = threadIdx.x;
  const int lane = tid & 63, wv = tid >> 6;
  const int wr = wv >> 1, wc = wv & 1;
  const int l15 = lane & 15, l4 = lane >> 4;

  f32x4 acc[4][4] = {};

  // A: lane reads float4 at (row=l15 of rowgroup i, col = ks*32 + t*16 + l4*4):
  // per instr 16 rows x 64B contiguous = 16 cache lines (minimum for f32).
  const float* ga = Wsrc + (size_t)(m0 + l15) * 768 + l4 * 4;
  const u16*   gb = wT + (size_t)(colbase + l15) * CH + l4 * 8;
  int aoff[4], boff[4];
#pragma unroll
  for (int u = 0; u < 4; ++u) {
    const int g = u * 4 + wv, i = g >> 1, ks = g & 1;
    aoff[u] = i * 16 * 768 + ks * 32;
    boff[u] = i * 16 * CH + ks * 32;
  }

  float4 areg0[4][2], areg1[4][2];
  auto loadA = [&](float4 (*ar)[2], int kk) {
#pragma unroll
    for (int u = 0; u < 4; ++u)
#pragma unroll
      for (int t = 0; t < 2; ++t)
        ar[u][t] = *reinterpret_cast<const float4*>(ga + kk + aoff[u] + t * 16);
  };
  auto stageB = [&](int bs, int kk) {
#pragma unroll
    for (int u = 0; u < 4; ++u)
      gload16(gb + kk + boff[u], &smem[bs][1][(u * 4 + wv) * 512]);
  };
  auto writeA = [&](float4 (*ar)[2], int bs) {
#pragma unroll
    for (int u = 0; u < 4; ++u) {
      const int g = u * 4 + wv;
#pragma unroll
      for (int t = 0; t < 2; ++t) {
        uint2 pkd;
        pkd.x = pk2(ar[u][t].x, ar[u][t].y);
        pkd.y = pk2(ar[u][t].z, ar[u][t].w);
        // element (row=l15, krel=t*16+l4*4): u16 idx = (t*2+(l4>>1))*128 + l15*8 + (l4&1)*4
        *reinterpret_cast<uint2*>(&smem[bs][0][g * 512 + (t * 2 + (l4 >> 1)) * 128 + l15 * 8 + (l4 & 1) * 4]) = pkd;
      }
    }
  };

  loadA(areg0, 0);   stageB(0, 0);    // 8 + 4 = 12
  loadA(areg1, 64);  stageB(1, 64);   // -> 24 outstanding

#pragma unroll
  for (int k = 0; k < 6; ++k) {
    if (k < 5) asm volatile("s_waitcnt vmcnt(12)" ::: "memory");   // stage k's A+B done; k+1 in flight
    else       asm volatile("s_waitcnt vmcnt(0)" ::: "memory");
    const int cb = k & 1;
    if (cb == 0) writeA(areg0, 0); else writeA(areg1, 1);
    asm volatile("s_waitcnt lgkmcnt(0)" ::: "memory");
    __builtin_amdgcn_s_barrier();
    __builtin_amdgcn_sched_barrier(0);
#pragma unroll
    for (int ks = 0; ks < 2; ++ks) {
      short8 af[4], bfr[4];
#pragma unroll
      for (int i = 0; i < 4; ++i)
        af[i] = *reinterpret_cast<const short8*>(&smem[cb][0][((wr * 4 + i) * 2 + ks) * 512 + lane * 8]);
#pragma unroll
      for (int j = 0; j < 4; ++j)
        bfr[j] = *reinterpret_cast<const short8*>(&smem[cb][1][((wc * 4 + j) * 2 + ks) * 512 + lane * 8]);
#pragma unroll
      for (int i = 0; i < 4; ++i)
#pragma unroll
        for (int j = 0; j < 4; ++j)
          acc[i][j] = __builtin_amdgcn_mfma_f32_16x16x32_bf16(af[i], bfr[j], acc[i][j], 0, 0, 0);
    }
    asm volatile("s_waitcnt lgkmcnt(0)" ::: "memory");
    __builtin_amdgcn_s_barrier();
    __builtin_amdgcn_sched_barrier(0);
    if (k + 2 < 6) {
      if (cb == 0) loadA(areg0, (k + 2) * 64); else loadA(areg1, (k + 2) * 64);
      stageB(cb, (k + 2) * 64);
    }
  }

#pragma unroll
  for (int j = 0; j < 4; ++j) {
    const int col = colbase + wc * 64 + j * 16 + l15;
    const float bb = bias[col];
#pragma unroll
    for (int i = 0; i < 4; ++i) {
#pragma unroll
      for (int r = 0; r < 4; ++r) {
        const int gm = m0 + wr * 64 + i * 16 + l4 * 4 + r;
        outx[(size_t)gm * CH + col] = acc[i][j][r] + bb;
      }
    }
  }
}

extern "C" void kernel_launch(void* const* d_in, const int* in_sizes, int n_in,
                              void* d_out, int out_size, void* d_ws, size_t ws_size,
                              hipStream_t stream) {
  const float* x1        = (const float*)d_in[0];
  const float* x2        = (const float*)d_in[1];
  const float* mask1     = (const float*)d_in[2];
  const float* mask2     = (const float*)d_in[3];
  const float* w_qkv     = (const float*)d_in[4];
  const float* b_qkv     = (const float*)d_in[5];
  const float* w_proj    = (const float*)d_in[6];
  const float* b_proj    = (const float*)d_in[7];
  const float* rpb_table = (const float*)d_in[8];
  const int*   rel_index = (const int*)d_in[9];

  float* outx = (float*)d_out;                      // [2048,49,384] f32
  const size_t SZe = (size_t)NB * NH * NTOK * HD;   // 38,535,168 elements
  float* outw = outx + SZe;                         // [2048,49,768] f32

  // q1,k1 (bf16) live in the x-region of d_out; proj writes x last.
  u16* q1 = (u16*)d_out;
  u16* k1 = q1 + SZe;
  // xb1,xb2 (bf16 copies of x1,x2) live in the outw region; attn overwrites later.
  u16* xb1 = (u16*)outw;
  u16* xb2 = xb1 + SZe;

  u16* v1 = (u16*)d_ws;
  u16* k2 = v1 + SZe;
  u16* v2 = k2 + SZe;
  u16* wqkvT  = v2 + SZe;              // [1152][384] bf16
  u16* wprojT = wqkvT + 1152 * 384;    // [384][384] bf16
  float* rpb  = (float*)(wprojT + 384 * 384);  // [12][49][49] f32

  {
    int total = 1152 * 384 + 384 * 384 + 12 * 2401;
    prep_kernel<<<(total + 255) / 256, 256, 0, stream>>>(w_qkv, w_proj, rpb_table, rel_index,
                                                         wqkvT, wprojT, rpb);
  }
  conv_bf16<<<(int)(SZe / (256 * 8)), 256, 0, stream>>>(x1, x2, xb1, xb2);
  gemm_qkv<<<11760, 256, 0, stream>>>(xb1, xb2, wqkvT, b_qkv, q1, k1, v1, k2, v2);
  attn_kernel<<<dim3(12, 2048), 256, 0, stream>>>(q1, k1, v1, k2, v2, mask1, mask2, rpb, outw);
  gemm_proj<<<2352, 256, 0, stream>>>(outw, wprojT, b_proj, outx);
}

// Round 7
// 734.025 us; speedup vs baseline: 3.6007x; 1.1595x over previous
//
#include <hip/hip_runtime.h>

typedef unsigned short u16;
typedef unsigned int u32;
typedef __attribute__((ext_vector_type(8))) short short8;
typedef __attribute__((ext_vector_type(4))) float f32x4;

#define NB 2048
#define NTOK 49
#define CH 384
#define NH 12
#define HD 32
#define SCALE_Q 0.17677669529663687f
#define TABF 1956864   // 768 * 49 * 52

__device__ __forceinline__ u16 f2bf(float f) {
  u32 u = __float_as_uint(f);
  u += 0x7fffu + ((u >> 16) & 1u);
  return (u16)(u >> 16);
}
__device__ __forceinline__ float bf2f(u16 h) { return __uint_as_float(((u32)h) << 16); }
__device__ __forceinline__ u32 pk2(float a, float b) { return (u32)f2bf(a) | ((u32)f2bf(b) << 16); }

// async global->LDS, 16B per lane, LDS dest = wave-uniform base + lane*16
__device__ __forceinline__ void gload16(const u16* g, u16* l) {
  __builtin_amdgcn_global_load_lds(
      (const __attribute__((address_space(1))) u32*)g,
      (__attribute__((address_space(3))) u32*)l,
      16, 0, 0);
}

// ---------- prep_w: transpose weights to bf16 ----------
__global__ void prep_w(const float* __restrict__ w_qkv, const float* __restrict__ w_proj,
                       u16* __restrict__ wqkvT, u16* __restrict__ wprojT)
{
  int idx = blockIdx.x * 256 + threadIdx.x;
  if (idx < 1152 * 384) {
    int n = idx / 384, k = idx - n * 384;
    wqkvT[idx] = f2bf(w_qkv[(size_t)k * 1152 + n]);
  } else if (idx < 1152 * 384 + 384 * 384) {
    int i2 = idx - 1152 * 384;
    int n = i2 / 384, k = i2 - n * 384;
    wprojT[i2] = f2bf(w_proj[(size_t)k * 384 + n]);
  }
}

// ---------- prep_c: combined bias tables comb[p][wb][h][i][52] = rpb + mask ----------
__global__ __launch_bounds__(256) void prep_c(const float* __restrict__ rpb_table,
                                              const int* __restrict__ rel_index,
                                              const float* __restrict__ mask1,
                                              const float* __restrict__ mask2,
                                              float* __restrict__ comb)
{
  const int wbh = blockIdx.x;            // 0..767 = wb*12 + h
  const int wb = wbh / 12, h = wbh - wb * 12;
  const size_t ob = (size_t)wbh * (49 * 52);
  for (int r = threadIdx.x; r < 2401; r += 256) {
    int i = r / 49, j = r - i * 49;
    float rv = rpb_table[(size_t)rel_index[r] * 12 + h];
    comb[ob + i * 52 + j]        = rv + mask1[(size_t)wb * 2401 + r];
    comb[TABF + ob + i * 52 + j] = rv + mask2[(size_t)wb * 2401 + r];
  }
}

// ---------- convert x1,x2 f32 -> bf16 (8 elems/thread) ----------
__global__ __launch_bounds__(256) void conv_bf16(const float* __restrict__ x1, const float* __restrict__ x2,
                                                 u16* __restrict__ xb1, u16* __restrict__ xb2)
{
  const size_t i = ((size_t)blockIdx.x * 256 + threadIdx.x) * 8;
  float4 a = *reinterpret_cast<const float4*>(x1 + i);
  float4 b = *reinterpret_cast<const float4*>(x1 + i + 4);
  uint4 o;
  o.x = pk2(a.x, a.y); o.y = pk2(a.z, a.w); o.z = pk2(b.x, b.y); o.w = pk2(b.z, b.w);
  *reinterpret_cast<uint4*>(xb1 + i) = o;
  a = *reinterpret_cast<const float4*>(x2 + i);
  b = *reinterpret_cast<const float4*>(x2 + i + 4);
  o.x = pk2(a.x, a.y); o.y = pk2(a.z, a.w); o.z = pk2(b.x, b.y); o.w = pk2(b.z, b.w);
  *reinterpret_cast<uint4*>(xb2 + i) = o;
}

// ---------- QKV GEMM: counted-vmcnt pipeline, global_load_lds staging ----------
__global__ __launch_bounds__(256) void gemm_qkv(
    const u16* __restrict__ xb1, const u16* __restrict__ xb2,
    const u16* __restrict__ wT, const float* __restrict__ bias,
    u16* __restrict__ q1, u16* __restrict__ k1, u16* __restrict__ v1,
    u16* __restrict__ k2, u16* __restrict__ v2)
{
  __shared__ __align__(16) u16 smem[2][2][8192];  // [buf][A/B][16 blocks x 512] = 64KB
  u16* Cs = &smem[0][0][0];                       // epilogue alias [128][152]

  // bijective XCD-chunked swizzle: 11760 = 8 * 1470
  const int bid0 = blockIdx.x;
  const int lin = (bid0 & 7) * 1470 + (bid0 >> 3);
  const int mt = lin / 15;
  const int nt = lin - mt * 15;

  const bool isx2 = nt >= 9;
  const u16* __restrict__ X = isx2 ? xb2 : xb1;
  const int colbase = isx2 ? 384 + (nt - 9) * 128 : nt * 128;
  const int m0 = mt * 128;
  const int tid = threadIdx.x;
  const int lane = tid & 63, wv = tid >> 6;
  const int wr = wv >> 1, wc = wv & 1;
  const int l15 = lane & 15, l4 = lane >> 4;

  f32x4 acc[4][4] = {};

  const u16* ga = X + (size_t)(m0 + l15) * CH + l4 * 8;
  const u16* gb = wT + (size_t)(colbase + l15) * CH + l4 * 8;
  int goff[4];
#pragma unroll
  for (int u = 0; u < 4; ++u) {
    const int g = u * 4 + wv, i = g >> 1, ks = g & 1;
    goff[u] = i * 16 * CH + ks * 32;
  }

  auto stage = [&](int bs, int kk) {
#pragma unroll
    for (int u = 0; u < 4; ++u) {
      const int g = u * 4 + wv;
      gload16(ga + kk + goff[u], &smem[bs][0][g * 512]);
      gload16(gb + kk + goff[u], &smem[bs][1][g * 512]);
    }
  };

  stage(0, 0);     // 8 loads
  stage(1, 64);    // 8 loads -> 16 outstanding

#pragma unroll
  for (int k = 0; k < 6; ++k) {
    if (k < 5) asm volatile("s_waitcnt vmcnt(8)" ::: "memory");   // stage(k) done, stage(k+1) in flight
    else       asm volatile("s_waitcnt vmcnt(0)" ::: "memory");
    __builtin_amdgcn_s_barrier();
    __builtin_amdgcn_sched_barrier(0);
    const int cb = k & 1;
#pragma unroll
    for (int ks = 0; ks < 2; ++ks) {
      short8 af[4], bfr[4];
#pragma unroll
      for (int i = 0; i < 4; ++i)
        af[i] = *reinterpret_cast<const short8*>(&smem[cb][0][((wr * 4 + i) * 2 + ks) * 512 + lane * 8]);
#pragma unroll
      for (int j = 0; j < 4; ++j)
        bfr[j] = *reinterpret_cast<const short8*>(&smem[cb][1][((wc * 4 + j) * 2 + ks) * 512 + lane * 8]);
#pragma unroll
      for (int i = 0; i < 4; ++i)
#pragma unroll
        for (int j = 0; j < 4; ++j)
          acc[i][j] = __builtin_amdgcn_mfma_f32_16x16x32_bf16(af[i], bfr[j], acc[i][j], 0, 0, 0);
    }
    asm volatile("s_waitcnt lgkmcnt(0)" ::: "memory");
    __builtin_amdgcn_s_barrier();
    __builtin_amdgcn_sched_barrier(0);
    if (k + 2 < 6) stage(cb, (k + 2) * 64);   // refill freed buffer; stays in flight across barriers
  }

  // ---- epilogue: bias+scale+pack into LDS, then coalesced 16B writes ----
#pragma unroll
  for (int j = 0; j < 4; ++j) {
    const int colL = wc * 64 + j * 16 + l15;
    const int gcol = colbase + colL;
    const float bb = bias[gcol];
    const float scl = (gcol < 384) ? SCALE_Q : 1.0f;
#pragma unroll
    for (int i = 0; i < 4; ++i)
#pragma unroll
      for (int r = 0; r < 4; ++r) {
        const int row = wr * 64 + i * 16 + l4 * 4 + r;
        Cs[row * 152 + (colL ^ (((row >> 2) & 3) << 3))] = f2bf((acc[i][j][r] + bb) * scl);
      }
  }
  __syncthreads();

  u16* dst;
  int tb;
  if (colbase < 384)      { dst = q1;              tb = colbase; }
  else if (colbase < 768) { dst = isx2 ? k2 : k1;  tb = colbase - 384; }
  else                    { dst = isx2 ? v2 : v1;  tb = colbase - 768; }

#pragma unroll
  for (int u = 0; u < 8; ++u) {
    const int pc = tid + u * 256;           // 0..2047
    const int row = pc >> 4, pp = pc & 15;
    const uint4 val = *reinterpret_cast<const uint4*>(&Cs[row * 152 + ((pp ^ ((row >> 2) & 3)) << 3)]);
    const int gm = m0 + row;
    const int b = gm / 49, tok = gm - b * 49;
    const int cm = tb + pp * 8;
    const int h = cm >> 5, d0 = cm & 31;
    *reinterpret_cast<uint4*>(&dst[(((size_t)b * NH + h) * NTOK + tok) * HD + d0]) = val;
  }
}

// ---------- attention: swapped QK^T (lane-local rows), float4 combined bias ----------
// Wave wt owns i-columns wt*16..+15. S^T = mfma(K, Q): lane (l4,l15) holds
// S[j=jt*16+l4*4+r][i=wt*16+l15]  -> bias via float4 from comb (stride 52),
// softmax: 15 lane-local ops + shfl_xor(16,32). P -> operand-order LDS blocks,
// PV reads contiguous b128. Output layout identical to before.
__global__ __launch_bounds__(256) void attn_kernel(
    const u16* __restrict__ q1, const u16* __restrict__ k1, const u16* __restrict__ v1,
    const u16* __restrict__ k2, const u16* __restrict__ v2,
    const float* __restrict__ comb, float* __restrict__ outw)
{
  __shared__ __align__(16) u16 VT[2][32][72];  // [half][d][tok], tok padded to 64 (49.. zeroed)
  __shared__ __align__(16) u16 Pb[4][2][512];  // [wave][kt][operand-order block]

  const int h = blockIdx.x, b = blockIdx.y;
  const int tid = threadIdx.x;
  const int lane = tid & 63, wt = tid >> 6;
  const int l15 = lane & 15, l4 = lane >> 4;
  const size_t base = ((size_t)b * NH + h) * 1568;

  // stage V: uint4 gather (8 d at fixed tok) -> transposed scatter into VT
  for (int e = tid; e < 392; e += 256) {
    const int p = e >= 196;
    const int e2 = e - p * 196;
    const int tok = e2 >> 2, d8 = (e2 & 3) * 8;
    const u16* src = (p ? v2 : v1) + base + tok * 32 + d8;
    uint4 val = *reinterpret_cast<const uint4*>(src);
    const u16* pv = reinterpret_cast<const u16*>(&val);
#pragma unroll
    for (int q = 0; q < 8; ++q) VT[p][d8 + q][tok] = pv[q];
  }
  // zero pad tok 49..63
  for (int e = tid; e < 2 * 32 * 15; e += 256) {
    int p = (e >= 480) ? 1 : 0;
    int e2 = e - p * 480;
    int d = e2 / 15, j = 49 + (e2 - d * 15);
    VT[p][d][j] = 0;
  }

  const short8 aq = *reinterpret_cast<const short8*>(&q1[base + (wt * 16 + l15) * 32 + l4 * 8]);

  __syncthreads();

  const int wb = b & 63;
  const int irow = wt * 16 + l15;
  const float* cb0 = comb + ((size_t)(wb * 12 + h) * 49 + (irow < 49 ? irow : 48)) * 52;
  const size_t obase = (size_t)b * (NTOK * 768) + (size_t)h * 32;

#pragma unroll
  for (int p = 0; p < 2; ++p) {
    const u16* __restrict__ kp = p ? k2 : k1;
    const float* cbp = cb0 + (size_t)p * TABF;

    // S^T = K @ Q^T : 4 j-tiles
    f32x4 st[4];
    __builtin_amdgcn_s_setprio(1);
#pragma unroll
    for (int jt = 0; jt < 4; ++jt) {
      short8 bk = *reinterpret_cast<const short8*>(&kp[base + (jt * 16 + l15) * 32 + l4 * 8]);
      st[jt] = __builtin_amdgcn_mfma_f32_16x16x32_bf16(bk, aq, (f32x4){0.f, 0.f, 0.f, 0.f}, 0, 0, 0);
    }
    __builtin_amdgcn_s_setprio(0);

    // bias (vector) + invalid-j kill
#pragma unroll
    for (int jt = 0; jt < 4; ++jt) {
      const float4 c = *reinterpret_cast<const float4*>(cbp + jt * 16 + l4 * 4);
#pragma unroll
      for (int r = 0; r < 4; ++r) {
        const int j = jt * 16 + l4 * 4 + r;
        st[jt][r] = (j < 49) ? st[jt][r] + (&c.x)[r] : -1e30f;
      }
    }

    // softmax over j (per-lane 16 values + reduce across l4 groups)
    float mx = -1e30f;
#pragma unroll
    for (int jt = 0; jt < 4; ++jt)
#pragma unroll
      for (int r = 0; r < 4; ++r) mx = fmaxf(mx, st[jt][r]);
    mx = fmaxf(mx, __shfl_xor(mx, 16));
    mx = fmaxf(mx, __shfl_xor(mx, 32));
    float sm = 0.f;
#pragma unroll
    for (int jt = 0; jt < 4; ++jt)
#pragma unroll
      for (int r = 0; r < 4; ++r) {
        float e = __expf(st[jt][r] - mx);
        st[jt][r] = e;
        sm += e;
      }
    sm += __shfl_xor(sm, 16);
    sm += __shfl_xor(sm, 32);
    const float si = 1.f / sm;

    // P^T -> operand-order LDS (paired u32 stores), wave-private
#pragma unroll
    for (int jt = 0; jt < 4; ++jt) {
      const int kt = jt >> 1;
#pragma unroll
      for (int r = 0; r < 4; r += 2) {
        const u32 pkv = pk2(st[jt][r] * si, st[jt][r + 1] * si);
        const int jrel = (jt & 1) * 16 + l4 * 4 + r;
        const int off = ((jrel >> 3) << 7) + l15 * 8 + (jrel & 7);
        *reinterpret_cast<u32*>(&Pb[wt][kt][off]) = pkv;
      }
    }

    // O = P @ V
    f32x4 o[2] = {};
    __builtin_amdgcn_s_setprio(1);
#pragma unroll
    for (int kt = 0; kt < 2; ++kt) {
      short8 ap = *reinterpret_cast<const short8*>(&Pb[wt][kt][lane * 8]);
#pragma unroll
      for (int n2 = 0; n2 < 2; ++n2) {
        short8 bvf = *reinterpret_cast<const short8*>(&VT[p][n2 * 16 + l15][kt * 32 + l4 * 8]);
        o[n2] = __builtin_amdgcn_mfma_f32_16x16x32_bf16(ap, bvf, o[n2], 0, 0, 0);
      }
    }
    __builtin_amdgcn_s_setprio(0);

#pragma unroll
    for (int n2 = 0; n2 < 2; ++n2)
#pragma unroll
      for (int r = 0; r < 4; ++r) {
        const int i = wt * 16 + l4 * 4 + r;
        if (i < 49)
          outw[obase + (size_t)i * 768 + p * 384 + n2 * 16 + l15] = o[n2][r];
      }
  }
}

// ---------- proj GEMM: counted-vmcnt pipeline; A(f32) reg-staged coalesced, B via gload_lds ----------
__global__ __launch_bounds__(256) void gemm_proj(
    const float* __restrict__ Wsrc, const u16* __restrict__ wT,
    const float* __restrict__ bias, float* __restrict__ outx)
{
  __shared__ __align__(16) u16 smem[2][2][8192];  // 64KB
  // bijective XCD-chunked swizzle: 2352 = 8 * 294
  const int bid0 = blockIdx.x;
  const int lin = (bid0 & 7) * 294 + (bid0 >> 3);
  const int mt = lin / 3;
  const int nt = lin - mt * 3;

  const int colbase = nt * 128;
  const int m0 = mt * 128;
  const int tid = threadIdx.x;
  const int lane = tid & 63, wv = tid >> 6;
  const int wr = wv >> 1, wc = wv & 1;
  const int l15 = lane & 15, l4 = lane >> 4;

  f32x4 acc[4][4] = {};

  const float* ga = Wsrc + (size_t)(m0 + l15) * 768 + l4 * 4;
  const u16*   gb = wT + (size_t)(colbase + l15) * CH + l4 * 8;
  int aoff[4], boff[4];
#pragma unroll
  for (int u = 0; u < 4; ++u) {
    const int g = u * 4 + wv, i = g >> 1, ks = g & 1;
    aoff[u] = i * 16 * 768 + ks * 32;
    boff[u] = i * 16 * CH + ks * 32;
  }

  float4 areg0[4][2], areg1[4][2];
  auto loadA = [&](float4 (*ar)[2], int kk) {
#pragma unroll
    for (int u = 0; u < 4; ++u)
#pragma unroll
      for (int t = 0; t < 2; ++t)
        ar[u][t] = *reinterpret_cast<const float4*>(ga + kk + aoff[u] + t * 16);
  };
  auto stageB = [&](int bs, int kk) {
#pragma unroll
    for (int u = 0; u < 4; ++u)
      gload16(gb + kk + boff[u], &smem[bs][1][(u * 4 + wv) * 512]);
  };
  auto writeA = [&](float4 (*ar)[2], int bs) {
#pragma unroll
    for (int u = 0; u < 4; ++u) {
      const int g = u * 4 + wv;
#pragma unroll
      for (int t = 0; t < 2; ++t) {
        uint2 pkd;
        pkd.x = pk2(ar[u][t].x, ar[u][t].y);
        pkd.y = pk2(ar[u][t].z, ar[u][t].w);
        *reinterpret_cast<uint2*>(&smem[bs][0][g * 512 + (t * 2 + (l4 >> 1)) * 128 + l15 * 8 + (l4 & 1) * 4]) = pkd;
      }
    }
  };

  loadA(areg0, 0);   stageB(0, 0);
  loadA(areg1, 64);  stageB(1, 64);

#pragma unroll
  for (int k = 0; k < 6; ++k) {
    if (k < 5) asm volatile("s_waitcnt vmcnt(12)" ::: "memory");
    else       asm volatile("s_waitcnt vmcnt(0)" ::: "memory");
    const int cb = k & 1;
    if (cb == 0) writeA(areg0, 0); else writeA(areg1, 1);
    asm volatile("s_waitcnt lgkmcnt(0)" ::: "memory");
    __builtin_amdgcn_s_barrier();
    __builtin_amdgcn_sched_barrier(0);
#pragma unroll
    for (int ks = 0; ks < 2; ++ks) {
      short8 af[4], bfr[4];
#pragma unroll
      for (int i = 0; i < 4; ++i)
        af[i] = *reinterpret_cast<const short8*>(&smem[cb][0][((wr * 4 + i) * 2 + ks) * 512 + lane * 8]);
#pragma unroll
      for (int j = 0; j < 4; ++j)
        bfr[j] = *reinterpret_cast<const short8*>(&smem[cb][1][((wc * 4 + j) * 2 + ks) * 512 + lane * 8]);
#pragma unroll
      for (int i = 0; i < 4; ++i)
#pragma unroll
        for (int j = 0; j < 4; ++j)
          acc[i][j] = __builtin_amdgcn_mfma_f32_16x16x32_bf16(af[i], bfr[j], acc[i][j], 0, 0, 0);
    }
    asm volatile("s_waitcnt lgkmcnt(0)" ::: "memory");
    __builtin_amdgcn_s_barrier();
    __builtin_amdgcn_sched_barrier(0);
    if (k + 2 < 6) {
      if (cb == 0) loadA(areg0, (k + 2) * 64); else loadA(areg1, (k + 2) * 64);
      stageB(cb, (k + 2) * 64);
    }
  }

#pragma unroll
  for (int j = 0; j < 4; ++j) {
    const int col = colbase + wc * 64 + j * 16 + l15;
    const float bb = bias[col];
#pragma unroll
    for (int i = 0; i < 4; ++i) {
#pragma unroll
      for (int r = 0; r < 4; ++r) {
        const int gm = m0 + wr * 64 + i * 16 + l4 * 4 + r;
        outx[(size_t)gm * CH + col] = acc[i][j][r] + bb;
      }
    }
  }
}

extern "C" void kernel_launch(void* const* d_in, const int* in_sizes, int n_in,
                              void* d_out, int out_size, void* d_ws, size_t ws_size,
                              hipStream_t stream) {
  const float* x1        = (const float*)d_in[0];
  const float* x2        = (const float*)d_in[1];
  const float* mask1     = (const float*)d_in[2];
  const float* mask2     = (const float*)d_in[3];
  const float* w_qkv     = (const float*)d_in[4];
  const float* b_qkv     = (const float*)d_in[5];
  const float* w_proj    = (const float*)d_in[6];
  const float* b_proj    = (const float*)d_in[7];
  const float* rpb_table = (const float*)d_in[8];
  const int*   rel_index = (const int*)d_in[9];

  float* outx = (float*)d_out;                      // [2048,49,384] f32
  const size_t SZe = (size_t)NB * NH * NTOK * HD;   // 38,535,168 elements
  float* outw = outx + SZe;                         // [2048,49,768] f32

  // q1,k1 (bf16) live in the x-region of d_out; proj writes x last.
  u16* q1 = (u16*)d_out;
  u16* k1 = q1 + SZe;
  // xb1,xb2 (bf16 copies of x1,x2) live in the outw region; attn overwrites later.
  u16* xb1 = (u16*)outw;
  u16* xb2 = xb1 + SZe;

  u16* v1 = (u16*)d_ws;
  u16* k2 = v1 + SZe;
  u16* v2 = k2 + SZe;
  u16* wqkvT  = v2 + SZe;              // [1152][384] bf16
  u16* wprojT = wqkvT + 1152 * 384;    // [384][384] bf16
  float* comb = (float*)(wprojT + 384 * 384);  // 2 x [64][12][49][52] f32 = 15.7MB

  prep_w<<<2304, 256, 0, stream>>>(w_qkv, w_proj, wqkvT, wprojT);
  prep_c<<<768, 256, 0, stream>>>(rpb_table, rel_index, mask1, mask2, comb);
  conv_bf16<<<(int)(SZe / (256 * 8)), 256, 0, stream>>>(x1, x2, xb1, xb2);
  gemm_qkv<<<11760, 256, 0, stream>>>(xb1, xb2, wqkvT, b_qkv, q1, k1, v1, k2, v2);
  attn_kernel<<<dim3(12, 2048), 256, 0, stream>>>(q1, k1, v1, k2, v2, comb, outw);
  gemm_proj<<<2352, 256, 0, stream>>>(outw, wprojT, b_proj, outx);
}